// Round 7
// baseline (7236.720 us; speedup 1.0000x reference)
//
#include <hip/hip_runtime.h>

typedef unsigned short u16;
typedef __attribute__((ext_vector_type(8))) short short8;
typedef __attribute__((ext_vector_type(4))) float f32x4;

__device__ __forceinline__ float b2f(u16 h) {
  union { unsigned int u; float f; } v; v.u = ((unsigned int)h) << 16; return v.f;
}
__device__ __forceinline__ u16 f2b(float f) {
  union { float f; unsigned int u; } v; v.f = f;
  return (u16)((v.u + 0x7fffu + ((v.u >> 16) & 1u)) >> 16);
}

// async global->LDS, 16B per lane; dst must be wave-base + lane*16 (m97 pattern)
__device__ __forceinline__ void gload16(const u16* g, u16* l) {
  __builtin_amdgcn_global_load_lds(
      (const __attribute__((address_space(1))) void*)g,
      (__attribute__((address_space(3))) void*)l, 16, 0, 0);
}

#define SENC 1025
#define SPENC 1032
#define NBE 129
#define SDEC 1024
#define NBD 128
#define BATCH 32
#define MENC (BATCH * SPENC)  /* 33024 */
#define MDEC (BATCH * SDEC)   /* 32768 */

// ---------- beacon ----------
__global__ void beacon_k(float* out) { if (threadIdx.x == 0) out[0] = 1000.0f; }

// ---------- weight transpose + bf16 convert: WT[n][k] = bf16(W[k][n]) ----------
__global__ __launch_bounds__(256) void tr_k(const float* __restrict__ W, u16* __restrict__ WT, int K, int N)
{
  __shared__ float sm[32][33];
  int k0 = blockIdx.x * 32, n0 = blockIdx.y * 32;
  const float* Wz = W + (size_t)blockIdx.z * K * N;
  u16* WTz = WT + (size_t)blockIdx.z * K * N;
  int r = threadIdx.x >> 3, c0 = (threadIdx.x & 7) * 4;
  float4 v = *(const float4*)&Wz[(size_t)(k0 + r) * N + n0 + c0];
  sm[r][c0] = v.x; sm[r][c0 + 1] = v.y; sm[r][c0 + 2] = v.z; sm[r][c0 + 3] = v.w;
  __syncthreads();
  ushort4 u;
  u.x = f2b(sm[c0][r]); u.y = f2b(sm[c0 + 1][r]); u.z = f2b(sm[c0 + 2][r]); u.w = f2b(sm[c0 + 3][r]);
  *(ushort4*)&WTz[(size_t)(n0 + r) * K + k0 + c0] = u;
}

// ---------- embed: h fp32 + hb bf16 ----------
__global__ __launch_bounds__(256) void embed_k(const float* __restrict__ x, const float* __restrict__ Wd,
    const float* __restrict__ bd, const float* __restrict__ emb, float* __restrict__ h, u16* __restrict__ hb)
{
  size_t gid = (size_t)blockIdx.x * 256 + threadIdx.x;  // MENC*512
  int dd = (int)(gid & 511);
  size_t rs = gid >> 9;
  int s = (int)(rs % SPENC);
  int b = (int)(rs / SPENC);
  float v;
  if (s == 0) {
    v = emb[dd];
  } else if (s < SENC) {
    float acc = bd[dd];
    const float* xr = x + ((size_t)b * 1024 + (s - 1)) * 16;
    #pragma unroll
    for (int j = 0; j < 16; ++j) acc += xr[j] * Wd[j * 512 + dd];
    v = acc + emb[(size_t)s * 512 + dd];
  } else {
    v = 0.f;
  }
  h[gid] = v;
  hb[gid] = f2b(v);
}

// ---------- MFMA bf16 GEMM, 256x256 tile, 1024 threads, 2-phase dbuf + XCD swizzle ----------
// C[M,N] = A[M,Ktot](bf16) @ WT[N,Ktot]^T(bf16) + bias (ReLU opt)
// ATOMIC: split-K over blockIdx.z; LDS-retiled epilogue, contiguous-lane f32 atomics.
// Non-atomic u16: LDS-retiled epilogue, coalesced short8 stores (2x16B per thread per slice).
// LDS chunk (16B = 8 bf16): logical k-chunk c of row r stored at slot r*4 + (c ^ ((r>>1)&3)).
template<typename TC, bool RELU, bool RESID, bool ATOMIC>
__global__ __launch_bounds__(1024) void mgemm_k(const u16* __restrict__ A, const u16* __restrict__ WT,
    const float* __restrict__ bias, const float* __restrict__ R, TC* __restrict__ C,
    int M, int N, int Kc, int lda, int ldb)
{
  __shared__ __align__(16) u16 smem[32768];   // 64 KB: staging dbuf (A 32KB | B 32KB), reused by epilogue
  int t = threadIdx.x;

  // bijective XCD-aware remap of the flattened (x,y) id
  int gx = gridDim.x;
  int nwg = gx * gridDim.y;
  int flat = blockIdx.y * gx + blockIdx.x;
  int q = nwg >> 3, rr = nwg & 7;
  int xcd = flat & 7, idx = flat >> 3;
  int swz = (xcd < rr ? xcd * (q + 1) : rr * (q + 1) + (xcd - rr) * q) + idx;
  int bx = swz % gx, by = swz / gx;

  int n0 = bx * 256, m0 = by * 256;
  int koff = blockIdx.z * Kc;
  int lane = t & 63, wave = t >> 6;            // 16 waves: 4x4 wave grid
  int wm = (wave >> 2) * 64, wn = (wave & 3) * 64;
  int quad = lane >> 4, l15 = lane & 15;

  // staging: thread t -> row t>>2 (0..255), slot t&3; one issue per matrix
  int rA = t >> 2, sc = t & 3;
  int cA = sc ^ ((rA >> 1) & 3);
  int raA = m0 + rA; raA = raA < M ? raA : M - 1;
  const u16* gA = A  + (size_t)raA * lda + koff + cA * 8;
  const u16* gB = WT + (size_t)(n0 + rA) * ldb + koff + cA * 8;
  u16* lA = &smem[t * 8];            // sA buf0; buf1 at +8192
  u16* lB = &smem[16384 + t * 8];    // sB buf0; buf1 at +8192

  f32x4 acc[4][4];
  #pragma unroll
  for (int i = 0; i < 4; ++i)
    #pragma unroll
    for (int j = 0; j < 4; ++j) acc[i][j] = (f32x4){0.f, 0.f, 0.f, 0.f};

  const int nt = Kc >> 5;
  // prologue: stage tile 0 into buf 0
  gload16(gA, lA); gload16(gB, lB);
  int cur = 0;
  for (int tt = 0; tt < nt; ++tt) {
    __syncthreads();  // drains vmcnt(0): buf[cur] ready; prior reads of buf[cur^1] done
    if (tt + 1 < nt) {
      int k0 = (tt + 1) << 5;
      gload16(gA + k0, lA + (cur ^ 1) * 8192);
      gload16(gB + k0, lB + (cur ^ 1) * 8192);
    }
    short8 af[4], bf[4];
    #pragma unroll
    for (int i = 0; i < 4; ++i) {
      int ra = wm + i * 16 + l15;
      af[i] = *(const short8*)&smem[cur * 8192 + ra * 32 + (quad ^ ((ra >> 1) & 3)) * 8];
    }
    #pragma unroll
    for (int j = 0; j < 4; ++j) {
      int rb = wn + j * 16 + l15;
      bf[j] = *(const short8*)&smem[16384 + cur * 8192 + rb * 32 + (quad ^ ((rb >> 1) & 3)) * 8];
    }
    #pragma unroll
    for (int i = 0; i < 4; ++i)
      #pragma unroll
      for (int j = 0; j < 4; ++j)
        acc[i][j] = __builtin_amdgcn_mfma_f32_16x16x32_bf16(af[i], bf[j], acc[i][j], 0, 0, 0);
    cur ^= 1;
  }

  // ---------- LDS-retiled epilogue (coalesced writes) ----------
  // acc layout: m = m0 + (wave>>2)*64 + i*16 + quad*4 + r ; n = n0 + (wave&3)*64 + j*16 + l15
  __syncthreads();  // all frag reads of final tile done before LDS reuse
  if constexpr (ATOMIC) {
    float* cbf = (float*)smem;  // [64][256] f32 = 64 KB
    #pragma unroll
    for (int i = 0; i < 4; ++i) {
      #pragma unroll
      for (int j = 0; j < 4; ++j) {
        int col = wn + j * 16 + l15;
        float bsv = (blockIdx.z == 0) ? bias[n0 + col] : 0.f;
        #pragma unroll
        for (int r = 0; r < 4; ++r) {
          int row_l = (wave >> 2) * 16 + quad * 4 + r;
          cbf[row_l * 256 + col] = acc[i][j][r] + bsv;
        }
      }
      __syncthreads();
      {
        int col = t & 255, rowg = t >> 8;  // lanes = consecutive cols -> 256B contiguous atomics
        #pragma unroll
        for (int rr2 = 0; rr2 < 16; ++rr2) {
          int grow = m0 + rowg * 64 + i * 16 + rr2;
          if (grow < M)
            unsafeAtomicAdd(&((float*)C)[(size_t)grow * N + n0 + col],
                            cbf[(rowg * 16 + rr2) * 256 + col]);
        }
      }
      __syncthreads();
    }
  } else if constexpr (sizeof(TC) == 2) {
    u16* cb = smem;  // [64][260] u16 (260 stride: conflict-spread deposits), 33.3 KB
    #pragma unroll
    for (int i = 0; i < 4; ++i) {
      #pragma unroll
      for (int j = 0; j < 4; ++j) {
        int col = wn + j * 16 + l15;
        float bsv = bias[n0 + col];
        #pragma unroll
        for (int r = 0; r < 4; ++r) {
          int row_l = (wave >> 2) * 16 + quad * 4 + r;
          float v = acc[i][j][r] + bsv;
          if (RELU) v = fmaxf(v, 0.f);
          cb[row_l * 260 + col] = f2b(v);
        }
      }
      __syncthreads();
      {
        int row_l = t >> 4, c0 = (t & 15) * 16;
        int grow = m0 + (row_l >> 4) * 64 + i * 16 + (row_l & 15);
        if (grow < M) {
          short8 w0 = *(const short8*)&cb[row_l * 260 + c0];
          short8 w1 = *(const short8*)&cb[row_l * 260 + c0 + 8];
          u16* dst = (u16*)C + (size_t)grow * N + n0 + c0;
          *(short8*)dst = w0;
          *(short8*)(dst + 8) = w1;
        }
      }
      __syncthreads();
    }
  } else {
    // f32 direct path (unused by current call sites) — scalar fallback
    #pragma unroll
    for (int i = 0; i < 4; ++i) {
      int mBase = m0 + wm + i * 16 + quad * 4;
      #pragma unroll
      for (int r = 0; r < 4; ++r) {
        int m = mBase + r;
        if (m < M) {
          #pragma unroll
          for (int j = 0; j < 4; ++j) {
            int n = n0 + wn + j * 16 + l15;
            float v = acc[i][j][r] + bias[n];
            if (RESID) v += R[(size_t)m * N + n];
            if (RELU) v = fmaxf(v, 0.f);
            ((float*)C)[(size_t)m * N + n] = v;
          }
        }
      }
    }
  }
}

// ---------- in-place LayerNorm, also emits bf16 shadow ----------
__global__ __launch_bounds__(256) void ln_k(float* h, u16* __restrict__ hb,
    const float* __restrict__ g, const float* __restrict__ bb)
{
  __shared__ float rs[256], rq[256];
  float* p = h + (size_t)blockIdx.x * 512;
  u16* pb = hb + (size_t)blockIdx.x * 512;
  int t = threadIdx.x;
  float v0 = p[t], v1 = p[t + 256];
  rs[t] = v0 + v1; rq[t] = v0 * v0 + v1 * v1;
  __syncthreads();
  for (int o = 128; o > 0; o >>= 1) {
    if (t < o) { rs[t] += rs[t + o]; rq[t] += rq[t + o]; }
    __syncthreads();
  }
  float mean = rs[0] * (1.f / 512.f);
  float var = fmaxf(rq[0] * (1.f / 512.f) - mean * mean, 0.f);
  float rinv = rsqrtf(var + 1e-5f);
  float o0 = (v0 - mean) * rinv * g[t] + bb[t];
  float o1 = (v1 - mean) * rinv * g[t + 256] + bb[t + 256];
  p[t] = o0; p[t + 256] = o1;
  pb[t] = f2b(o0); pb[t + 256] = f2b(o1);
}

// ---------- sparse block attention, MFMA version: one wave per (b, h, n) ----------
__global__ __launch_bounds__(64) void attnm_k(const u16* __restrict__ qkv, u16* __restrict__ av,
    const int* __restrict__ rnd, int S, int Sp, int nb)
{
  __shared__ __align__(16) u16 Vt[64 * 104];
  __shared__ __align__(16) u16 Pl[16 * 104];
  __shared__ int sJB[10], sVD[10];
  int t = threadIdx.x;
  int n = blockIdx.x % nb;
  int r1 = blockIdx.x / nb;
  int hh = r1 & 7, b = r1 >> 3;
  const u16* base = qkv + (size_t)b * Sp * 1536;
  int l15 = t & 15, quad = t >> 4;

  if (t < 10) {
    int jb, vd;
    if (t < 2) { jb = t; vd = 1; }
    else if (t < 7) {
      int w = n + t - 4;
      vd = (w >= 0 && w < nb) ? 1 : 0;
      jb = w < 0 ? 0 : (w > nb - 1 ? nb - 1 : w);
    } else { jb = rnd[n * 3 + t - 7]; vd = 1; }
    sJB[t] = jb; sVD[t] = vd;
  }
  {
    f32x4 zz = {0.f, 0.f, 0.f, 0.f};
    *(f32x4*)&Vt[t * 104 + 80] = zz;
    *(f32x4*)&Vt[t * 104 + 88] = zz;
    if (t < 16) {
      *(f32x4*)&Pl[t * 104 + 80] = zz;
      *(f32x4*)&Pl[t * 104 + 88] = zz;
    }
  }
  __syncthreads();

  short8 aq0, aq1;
  {
    const u16* qp = base + (size_t)(n * 8 + (l15 & 7)) * 1536 + hh * 64 + quad * 8;
    aq0 = *(const short8*)qp;
    aq1 = *(const short8*)(qp + 32);
  }

  f32x4 s[5];
  float okm[5];
  #pragma unroll
  for (int tile = 0; tile < 5; ++tile) {
    int kb = tile * 2 + (l15 >> 3);
    int tok = sJB[kb] * 8 + (l15 & 7);
    okm[tile] = (sVD[kb] && tok < S) ? 0.f : -3.0e38f;
    const u16* kp = base + (size_t)tok * 1536 + 512 + hh * 64 + quad * 8;
    short8 k0 = *(const short8*)kp;
    short8 k1 = *(const short8*)(kp + 32);
    f32x4 c = {0.f, 0.f, 0.f, 0.f};
    c = __builtin_amdgcn_mfma_f32_16x16x32_bf16(aq0, k0, c, 0, 0, 0);
    c = __builtin_amdgcn_mfma_f32_16x16x32_bf16(aq1, k1, c, 0, 0, 0);
    s[tile] = c;
  }

  u16 vreg[80];
  #pragma unroll
  for (int vt = 0; vt < 10; ++vt) {
    const u16* vp = base + (size_t)(sJB[vt] * 8) * 1536 + 1024 + hh * 64 + t;
    #pragma unroll
    for (int j = 0; j < 8; ++j) vreg[vt * 8 + j] = vp[(size_t)j * 1536];
  }

  f32x4 mx = {-3.0e38f, -3.0e38f, -3.0e38f, -3.0e38f};
  #pragma unroll
  for (int tile = 0; tile < 5; ++tile) {
    #pragma unroll
    for (int r = 0; r < 4; ++r) {
      float v = s[tile][r] * 0.125f + okm[tile];
      s[tile][r] = v;
      mx[r] = fmaxf(mx[r], v);
    }
  }
  #pragma unroll
  for (int off = 1; off < 16; off <<= 1) {
    #pragma unroll
    for (int r = 0; r < 4; ++r) mx[r] = fmaxf(mx[r], __shfl_xor(mx[r], off));
  }
  f32x4 sm = {0.f, 0.f, 0.f, 0.f};
  #pragma unroll
  for (int tile = 0; tile < 5; ++tile) {
    #pragma unroll
    for (int r = 0; r < 4; ++r) {
      float e = __expf(s[tile][r] - mx[r]);
      s[tile][r] = e;
      sm[r] += e;
    }
  }
  #pragma unroll
  for (int off = 1; off < 16; off <<= 1) {
    #pragma unroll
    for (int r = 0; r < 4; ++r) sm[r] += __shfl_xor(sm[r], off);
  }

  #pragma unroll
  for (int tile = 0; tile < 5; ++tile)
    #pragma unroll
    for (int r = 0; r < 4; ++r)
      Pl[(quad * 4 + r) * 104 + tile * 16 + l15] = f2b(s[tile][r]);

  #pragma unroll
  for (int vt = 0; vt < 10; ++vt) {
    short8 w;
    #pragma unroll
    for (int j = 0; j < 8; ++j) ((u16*)&w)[j] = (short)vreg[vt * 8 + j];
    *(short8*)&Vt[t * 104 + vt * 8] = w;
  }
  __syncthreads();

  f32x4 o[4];
  #pragma unroll
  for (int dn = 0; dn < 4; ++dn) o[dn] = (f32x4){0.f, 0.f, 0.f, 0.f};
  #pragma unroll
  for (int ks = 0; ks < 3; ++ks) {
    short8 ap = *(const short8*)&Pl[l15 * 104 + ks * 32 + quad * 8];
    #pragma unroll
    for (int dn = 0; dn < 4; ++dn) {
      short8 bv = *(const short8*)&Vt[(dn * 16 + l15) * 104 + ks * 32 + quad * 8];
      o[dn] = __builtin_amdgcn_mfma_f32_16x16x32_bf16(ap, bv, o[dn], 0, 0, 0);
    }
  }

  if (quad < 2) {
    #pragma unroll
    for (int r = 0; r < 4; ++r) {
      int qi = quad * 4 + r;
      float inv = 1.f / sm[r];
      u16* op = av + ((size_t)b * Sp + n * 8 + qi) * 512 + hh * 64 + l15;
      #pragma unroll
      for (int dn = 0; dn < 4; ++dn)
        op[dn * 16] = f2b(o[dn][r] * inv);
    }
  }
}

// ---------- VAE head ----------
__global__ __launch_bounds__(512) void head_k(const float* __restrict__ h,
    const float* __restrict__ Wm, const float* __restrict__ bm,
    const float* __restrict__ Wlv, const float* __restrict__ blv,
    const float* __restrict__ eps, float* __restrict__ z, float* out_elbo)
{
  __shared__ float red[512];
  int t = threadIdx.x;
  int b = t >> 4, i = t & 15;
  const float* p = h + (size_t)b * SPENC * 512;
  float am = bm[i], al = blv[i];
  for (int c = 0; c < 512; ++c) {
    float pv = p[c];
    am += pv * Wm[c * 16 + i];
    al += pv * Wlv[c * 16 + i];
  }
  z[t] = am + eps[t] * expf(0.5f * al);
  red[t] = -0.5f * (1.f + al - am * am - expf(al));
  __syncthreads();
  for (int o = 256; o > 0; o >>= 1) { if (t < o) red[t] += red[t + o]; __syncthreads(); }
  if (t == 0) out_elbo[0] = red[0] * (1.f / 32.f);
}

// ---------- seq ----------
__global__ __launch_bounds__(256) void seq_k(const float* __restrict__ z, const float* __restrict__ We,
    const float* __restrict__ be, float* __restrict__ seq)
{
  int gid = blockIdx.x * 256 + threadIdx.x;
  int b = gid >> 11, c = gid & 2047;
  float acc = be[c];
  #pragma unroll
  for (int i = 0; i < 16; ++i) acc += z[b * 16 + i] * We[i * 2048 + c];
  seq[gid] = acc;
}

// ---------- decoder init: h fp32 + hb bf16 ----------
__global__ __launch_bounds__(256) void decinit_k(const float* __restrict__ seq, const float* __restrict__ Wc,
    const float* __restrict__ bc, const float* __restrict__ emb, float* __restrict__ h, u16* __restrict__ hb)
{
  size_t gid = (size_t)blockIdx.x * 256 + threadIdx.x;
  int dd = (int)(gid & 511);
  size_t rs = gid >> 9;
  int s = (int)(rs & 1023);
  int b = (int)(rs >> 10);
  float v = seq[b * 2048 + s] * Wc[dd] + seq[b * 2048 + 1024 + s] * Wc[512 + dd]
          + bc[dd] + emb[(size_t)s * 512 + dd];
  h[gid] = v;
  hb[gid] = f2b(v);
}

// ---------- final ----------
__global__ __launch_bounds__(256) void final_k(const float* __restrict__ h, const float* __restrict__ Ws,
    const float* __restrict__ bs, float* __restrict__ out)
{
  int gid = blockIdx.x * 256 + threadIdx.x;
  int nn = gid & 15;
  int rs = gid >> 4;
  const float* p = h + (size_t)rs * 512;
  float acc = bs[nn];
  for (int c = 0; c < 512; ++c) acc += p[c] * Ws[c * 16 + nn];
  out[gid] = acc;
}

extern "C" void kernel_launch(void* const* d_in, const int* in_sizes, int n_in,
                              void* d_out, int out_size, void* d_ws, size_t ws_size,
                              hipStream_t stream) {
  float* out = (float*)d_out;
  (void)out_size; (void)ws_size;

  static const int EXP_DICT[30] = {
    524288, 512, 524800, 524288, 8192, 512, 7864320, 15360, 2621440, 5120,
    5120, 5120, 10485760, 20480, 10485760, 5120, 5120, 5120, 8192, 16,
    8192, 16, 32768, 2048, 1024, 512, 8192, 16, 387, 384 };
  bool dict_ok = (n_in == 30);
  if (dict_ok) for (int i = 0; i < 30; ++i) if (in_sizes[i] != EXP_DICT[i]) { dict_ok = false; break; }
  if (!dict_ok) { beacon_k<<<1, 64, 0, stream>>>(out); return; }

  const float* x      = (const float*)d_in[0];
  const float* eps    = (const float*)d_in[1];
  const float* emb_in = (const float*)d_in[2];
  const float* emb_out= (const float*)d_in[3];
  const float* W_data = (const float*)d_in[4];
  const float* b_data = (const float*)d_in[5];
  const float* Wqkv   = (const float*)d_in[6];
  const float* bqkv   = (const float*)d_in[7];
  const float* Wo     = (const float*)d_in[8];
  const float* bo     = (const float*)d_in[9];
  const float* ln1g   = (const float*)d_in[10];
  const float* ln1b   = (const float*)d_in[11];
  const float* W1     = (const float*)d_in[12];
  const float* b1     = (const float*)d_in[13];
  const float* W2     = (const float*)d_in[14];
  const float* b2     = (const float*)d_in[15];
  const float* ln2g   = (const float*)d_in[16];
  const float* ln2b   = (const float*)d_in[17];
  const float* Wm     = (const float*)d_in[18];
  const float* bm     = (const float*)d_in[19];
  const float* Wlv    = (const float*)d_in[20];
  const float* blv    = (const float*)d_in[21];
  const float* Wexp   = (const float*)d_in[22];
  const float* bexp   = (const float*)d_in[23];
  const float* Wconv  = (const float*)d_in[24];
  const float* bconv  = (const float*)d_in[25];
  const float* Wseq   = (const float*)d_in[26];
  const float* bseq   = (const float*)d_in[27];
  const int* rand_enc = (const int*)d_in[28];
  const int* rand_dec = (const int*)d_in[29];

  // ---- workspace carve (~194.5 MB; proven-safe envelope 203 MB) ----
  char* ws = (char*)d_ws;
  float* h     = (float*)ws;
  u16*   hb    = (u16*)(ws + 67633152);
  u16*   WTqkv = (u16*)(ws + 101449728);
  u16*   WTo   = (u16*)(ws + 117178368);
  u16*   WT1l  = (u16*)(ws + 122421248);
  u16*   WT2l  = (u16*)(ws + 124518400);
  u16*   qkvb  = (u16*)(ws + 126615552);
  u16*   avb   = (u16*)(ws + 126615552 + 50724864);
  u16*   ffnb  = (u16*)(ws + 126615552);             // union with qkvb+avb
  float* seqb  = (float*)(ws + 194248704);
  float* z     = (float*)(ws + 194510848);

  // ---- persistent weight transpose+convert (qkv, o for all 10 layers) ----
  tr_k<<<dim3(512 / 32, 1536 / 32, 10), 256, 0, stream>>>(Wqkv, WTqkv, 512, 1536);
  tr_k<<<dim3(512 / 32, 512 / 32, 10), 256, 0, stream>>>(Wo, WTo, 512, 512);

  // ===== encoder: M=33024; attention path in 2 chunks of 16 batches (Mc=16512) =====
  {
    const int M = MENC;
    embed_k<<<(M * 512) / 256, 256, 0, stream>>>(x, W_data, b_data, emb_in, h, hb);
    for (int i = 0; i < 5; ++i) {
      for (int bc = 0; bc < 2; ++bc) {
        size_t roff = (size_t)bc * 16 * SPENC * 512;
        const int Mc = 16 * SPENC;  // 16512
        const int ty = 65;          // ceil(16512/256)
        mgemm_k<u16, false, false, false><<<dim3(1536 / 256, ty, 1), 1024, 0, stream>>>(
            hb + roff, WTqkv + (size_t)i * 512 * 1536, bqkv + (size_t)i * 1536, nullptr, qkvb, Mc, 1536, 512, 512, 512);
        attnm_k<<<16 * 8 * NBE, 64, 0, stream>>>(qkvb, avb, rand_enc, SENC, SPENC, NBE);
        // Wo: split-K=2, atomic into h (h pre-holds residual)
        mgemm_k<float, false, false, true><<<dim3(512 / 256, ty, 2), 1024, 0, stream>>>(
            avb, WTo + (size_t)i * 512 * 512, bo + (size_t)i * 512, nullptr, h + roff, Mc, 512, 256, 512, 512);
      }
      ln_k<<<M, 256, 0, stream>>>(h, hb, ln1g + (size_t)i * 512, ln1b + (size_t)i * 512);
      // per-layer FFN weight transposes (WT1l/WT2l)
      tr_k<<<dim3(512 / 32, 2048 / 32, 1), 256, 0, stream>>>(W1 + (size_t)i * 512 * 2048, WT1l, 512, 2048);
      tr_k<<<dim3(2048 / 32, 512 / 32, 1), 256, 0, stream>>>(W2 + (size_t)i * 2048 * 512, WT2l, 2048, 512);
      for (int off = 0; off < M; off += 16512) {
        const int Mc = 16512;  // 33024 = 2 * 16512 exactly
        const int ty = 65;
        mgemm_k<u16, true, false, false><<<dim3(2048 / 256, ty, 1), 1024, 0, stream>>>(
            hb + (size_t)off * 512, WT1l, b1 + (size_t)i * 2048, nullptr, ffnb, Mc, 2048, 512, 512, 512);
        // W2: split-K=2 (Kc=1024), atomic into h (h pre-holds post-ln1 residual)
        mgemm_k<float, false, false, true><<<dim3(512 / 256, ty, 2), 1024, 0, stream>>>(
            ffnb, WT2l, b2 + (size_t)i * 512, nullptr, h + (size_t)off * 512, Mc, 512, 1024, 2048, 2048);
      }
      ln_k<<<M, 256, 0, stream>>>(h, hb, ln2g + (size_t)i * 512, ln2b + (size_t)i * 512);
    }
  }

  // ===== VAE head =====
  head_k<<<1, 512, 0, stream>>>(h, Wm, bm, Wlv, blv, eps, z, out + 524288);
  seq_k<<<256, 256, 0, stream>>>(z, Wexp, bexp, seqb);
  decinit_k<<<(MDEC * 512) / 256, 256, 0, stream>>>(seqb, Wconv, bconv, emb_out, h, hb);

  // ===== decoder: M=32768; attention path in 2 chunks of 16 batches (Mc=16384) =====
  {
    const int M = MDEC;
    for (int i = 5; i < 10; ++i) {
      for (int bc = 0; bc < 2; ++bc) {
        size_t roff = (size_t)bc * 16 * SDEC * 512;
        const int Mc = 16 * SDEC;  // 16384
        const int ty = 64;
        mgemm_k<u16, false, false, false><<<dim3(1536 / 256, ty, 1), 1024, 0, stream>>>(
            hb + roff, WTqkv + (size_t)i * 512 * 1536, bqkv + (size_t)i * 1536, nullptr, qkvb, Mc, 1536, 512, 512, 512);
        attnm_k<<<16 * 8 * NBD, 64, 0, stream>>>(qkvb, avb, rand_dec, SDEC, SDEC, NBD);
        mgemm_k<float, false, false, true><<<dim3(512 / 256, ty, 2), 1024, 0, stream>>>(
            avb, WTo + (size_t)i * 512 * 512, bo + (size_t)i * 512, nullptr, h + roff, Mc, 512, 256, 512, 512);
      }
      ln_k<<<M, 256, 0, stream>>>(h, hb, ln1g + (size_t)i * 512, ln1b + (size_t)i * 512);
      tr_k<<<dim3(512 / 32, 2048 / 32, 1), 256, 0, stream>>>(W1 + (size_t)i * 512 * 2048, WT1l, 512, 2048);
      tr_k<<<dim3(2048 / 32, 512 / 32, 1), 256, 0, stream>>>(W2 + (size_t)i * 2048 * 512, WT2l, 2048, 512);
      for (int off = 0; off < M; off += 16384) {
        const int Mc = 16384;
        const int ty = 64;
        mgemm_k<u16, true, false, false><<<dim3(2048 / 256, ty, 1), 1024, 0, stream>>>(
            hb + (size_t)off * 512, WT1l, b1 + (size_t)i * 2048, nullptr, ffnb, Mc, 2048, 512, 512, 512);
        mgemm_k<float, false, false, true><<<dim3(512 / 256, ty, 2), 1024, 0, stream>>>(
            ffnb, WT2l, b2 + (size_t)i * 512, nullptr, h + (size_t)off * 512, Mc, 512, 1024, 2048, 2048);
      }
      ln_k<<<M, 256, 0, stream>>>(h, hb, ln2g + (size_t)i * 512, ln2b + (size_t)i * 512);
    }
  }

  // ===== output =====
  final_k<<<524288 / 256, 256, 0, stream>>>(h, Wseq, bseq, out);
}

// Round 8
// 6722.992 us; speedup vs baseline: 1.0764x; 1.0764x over previous
//
#include <hip/hip_runtime.h>

typedef unsigned short u16;
typedef __attribute__((ext_vector_type(8))) short short8;
typedef __attribute__((ext_vector_type(4))) float f32x4;

__device__ __forceinline__ float b2f(u16 h) {
  union { unsigned int u; float f; } v; v.u = ((unsigned int)h) << 16; return v.f;
}
__device__ __forceinline__ u16 f2b(float f) {
  union { float f; unsigned int u; } v; v.f = f;
  return (u16)((v.u + 0x7fffu + ((v.u >> 16) & 1u)) >> 16);
}

// async global->LDS, 16B per lane; dst must be wave-base + lane*16 (m97 pattern)
__device__ __forceinline__ void gload16(const u16* g, u16* l) {
  __builtin_amdgcn_global_load_lds(
      (const __attribute__((address_space(1))) void*)g,
      (__attribute__((address_space(3))) void*)l, 16, 0, 0);
}

#define SENC 1025
#define SPENC 1032
#define NBE 129
#define SDEC 1024
#define NBD 128
#define BATCH 32
#define MENC (BATCH * SPENC)  /* 33024 */
#define MDEC (BATCH * SDEC)   /* 32768 */

// ---------- beacon ----------
__global__ void beacon_k(float* out) { if (threadIdx.x == 0) out[0] = 1000.0f; }

// ---------- weight transpose + bf16 convert: WT[n][k] = bf16(W[k][n]) ----------
__global__ __launch_bounds__(256) void tr_k(const float* __restrict__ W, u16* __restrict__ WT, int K, int N)
{
  __shared__ float sm[32][33];
  int k0 = blockIdx.x * 32, n0 = blockIdx.y * 32;
  const float* Wz = W + (size_t)blockIdx.z * K * N;
  u16* WTz = WT + (size_t)blockIdx.z * K * N;
  int r = threadIdx.x >> 3, c0 = (threadIdx.x & 7) * 4;
  float4 v = *(const float4*)&Wz[(size_t)(k0 + r) * N + n0 + c0];
  sm[r][c0] = v.x; sm[r][c0 + 1] = v.y; sm[r][c0 + 2] = v.z; sm[r][c0 + 3] = v.w;
  __syncthreads();
  ushort4 u;
  u.x = f2b(sm[c0][r]); u.y = f2b(sm[c0 + 1][r]); u.z = f2b(sm[c0 + 2][r]); u.w = f2b(sm[c0 + 3][r]);
  *(ushort4*)&WTz[(size_t)(n0 + r) * K + k0 + c0] = u;
}

// ---------- embed: h fp32 + hb bf16 ----------
__global__ __launch_bounds__(256) void embed_k(const float* __restrict__ x, const float* __restrict__ Wd,
    const float* __restrict__ bd, const float* __restrict__ emb, float* __restrict__ h, u16* __restrict__ hb)
{
  size_t gid = (size_t)blockIdx.x * 256 + threadIdx.x;  // MENC*512
  int dd = (int)(gid & 511);
  size_t rs = gid >> 9;
  int s = (int)(rs % SPENC);
  int b = (int)(rs / SPENC);
  float v;
  if (s == 0) {
    v = emb[dd];
  } else if (s < SENC) {
    float acc = bd[dd];
    const float* xr = x + ((size_t)b * 1024 + (s - 1)) * 16;
    #pragma unroll
    for (int j = 0; j < 16; ++j) acc += xr[j] * Wd[j * 512 + dd];
    v = acc + emb[(size_t)s * 512 + dd];
  } else {
    v = 0.f;
  }
  h[gid] = v;
  hb[gid] = f2b(v);
}

// ---------- MFMA bf16 GEMM, 128x256 tile, 512 threads (8 waves) ----------
// TRIPLE-buffered LDS + counted vmcnt (T3/T4): loads stay in flight across barriers.
// Per iter: s_waitcnt vmcnt(3) [tile t landed, t+1 flying] -> s_barrier -> issue tile t+2
//           -> ds_read frags -> setprio(1) MFMA setprio(0).
// Safety: barrier(t) implies all waves' iter t-1 ds_reads complete (lgkmcnt before MFMA),
// so overwriting buf (t+2)%3 == (t-1)%3 after barrier is race-free. vmcnt counts in-order.
// C[M,N] = A[M,Ktot](bf16) @ WT[N,Ktot]^T(bf16) + bias (+ReLU); ATOMIC: split-K unsafeAtomicAdd.
// LDS chunk (16B = 8 bf16): logical k-chunk c of row r stored at slot r*4 + (c ^ ((r>>1)&3)).
template<typename TC, bool RELU, bool RESID, bool ATOMIC>
__global__ __launch_bounds__(512) void mgemm_k(const u16* __restrict__ A, const u16* __restrict__ WT,
    const float* __restrict__ bias, const float* __restrict__ R, TC* __restrict__ C,
    int M, int N, int Kc, int lda, int ldb)
{
  __shared__ __align__(16) u16 sA[3][128 * 32];   // 24 KB
  __shared__ __align__(16) u16 sB[3][256 * 32];   // 48 KB
  int t = threadIdx.x;

  // bijective XCD-aware remap of the flattened (x,y) id
  int gx = gridDim.x;
  int nwg = gx * gridDim.y;
  int flat = blockIdx.y * gx + blockIdx.x;
  int q = nwg >> 3, rr = nwg & 7;
  int xcd = flat & 7, idx = flat >> 3;
  int swz = (xcd < rr ? xcd * (q + 1) : rr * (q + 1) + (xcd - rr) * q) + idx;
  int bx = swz % gx, by = swz / gx;

  int n0 = bx * 256, m0 = by * 128;
  int koff = blockIdx.z * Kc;
  int lane = t & 63, wave = t >> 6;            // 8 waves: 2M x 4N
  int wm = (wave >> 2) * 64, wn = (wave & 3) * 64;
  int quad = lane >> 4, l15 = lane & 15;

  // staging: A 1 issue (512 chunks), B 2 issues (1024 chunks); chunk ch -> row ch>>2, slot ch&3
  int rA = t >> 2, sc = t & 3;
  int cA = sc ^ ((rA >> 1) & 3);
  int raA = m0 + rA; raA = raA < M ? raA : M - 1;
  const u16* gA  = A  + (size_t)raA * lda + koff + cA * 8;
  const u16* gB0 = WT + (size_t)(n0 + rA) * ldb + koff + cA * 8;       // rows 0..127
  const u16* gB1 = WT + (size_t)(n0 + 128 + rA) * ldb + koff + cA * 8; // rows 128..255 (same xor)

  f32x4 acc[4][4];
  #pragma unroll
  for (int i = 0; i < 4; ++i)
    #pragma unroll
    for (int j = 0; j < 4; ++j) acc[i][j] = (f32x4){0.f, 0.f, 0.f, 0.f};

  const int nt = Kc >> 5;
  // prologue: stage tile 0 -> buf0, tile 1 -> buf1 (6 loads in flight per wave)
  gload16(gA,      &sA[0][t * 8]);
  gload16(gB0,     &sB[0][t * 8]);
  gload16(gB1,     &sB[0][(512 + t) * 8]);
  gload16(gA + 32, &sA[1][t * 8]);
  gload16(gB0 + 32,&sB[1][t * 8]);
  gload16(gB1 + 32,&sB[1][(512 + t) * 8]);

  int cur = 0;
  for (int tt = 0; tt < nt; ++tt) {
    if (tt < nt - 1) {
      asm volatile("s_waitcnt vmcnt(3)" ::: "memory");   // tile tt landed; tile tt+1 in flight
    } else {
      asm volatile("s_waitcnt vmcnt(0)" ::: "memory");
    }
    __builtin_amdgcn_s_barrier();
    asm volatile("" ::: "memory");
    if (tt + 2 < nt) {
      int k0 = (tt + 2) << 5;
      int nb = tt + 2; nb -= (nb / 3) * 3;               // (tt+2) % 3
      gload16(gA + k0,  &sA[nb][t * 8]);
      gload16(gB0 + k0, &sB[nb][t * 8]);
      gload16(gB1 + k0, &sB[nb][(512 + t) * 8]);
    }
    short8 af[4], bf[4];
    #pragma unroll
    for (int i = 0; i < 4; ++i) {
      int ra = wm + i * 16 + l15;
      af[i] = *(const short8*)&sA[cur][ra * 32 + (quad ^ ((ra >> 1) & 3)) * 8];
    }
    #pragma unroll
    for (int j = 0; j < 4; ++j) {
      int rb = wn + j * 16 + l15;
      bf[j] = *(const short8*)&sB[cur][rb * 32 + (quad ^ ((rb >> 1) & 3)) * 8];
    }
    __builtin_amdgcn_s_setprio(1);
    #pragma unroll
    for (int i = 0; i < 4; ++i)
      #pragma unroll
      for (int j = 0; j < 4; ++j)
        acc[i][j] = __builtin_amdgcn_mfma_f32_16x16x32_bf16(af[i], bf[j], acc[i][j], 0, 0, 0);
    __builtin_amdgcn_s_setprio(0);
    cur = (cur == 2) ? 0 : cur + 1;
  }

  // epilogue: D row = quad*4+reg (m), col = lane&15 (n)  [m89-verified]
  #pragma unroll
  for (int i = 0; i < 4; ++i) {
    int mBase = m0 + wm + i * 16 + quad * 4;
    #pragma unroll
    for (int r = 0; r < 4; ++r) {
      int m = mBase + r;
      if (m < M) {
        #pragma unroll
        for (int j = 0; j < 4; ++j) {
          int n = n0 + wn + j * 16 + l15;
          if constexpr (ATOMIC) {
            float v = acc[i][j][r];
            if (blockIdx.z == 0) v += bias[n];
            unsafeAtomicAdd(&((float*)C)[(size_t)m * N + n], v);
          } else {
            float v = acc[i][j][r] + bias[n];
            if (RESID) v += R[(size_t)m * N + n];
            if (RELU) v = fmaxf(v, 0.f);
            if constexpr (sizeof(TC) == 2) ((u16*)C)[(size_t)m * N + n] = f2b(v);
            else ((float*)C)[(size_t)m * N + n] = v;
          }
        }
      }
    }
  }
}

// ---------- in-place LayerNorm, also emits bf16 shadow ----------
__global__ __launch_bounds__(256) void ln_k(float* h, u16* __restrict__ hb,
    const float* __restrict__ g, const float* __restrict__ bb)
{
  __shared__ float rs[256], rq[256];
  float* p = h + (size_t)blockIdx.x * 512;
  u16* pb = hb + (size_t)blockIdx.x * 512;
  int t = threadIdx.x;
  float v0 = p[t], v1 = p[t + 256];
  rs[t] = v0 + v1; rq[t] = v0 * v0 + v1 * v1;
  __syncthreads();
  for (int o = 128; o > 0; o >>= 1) {
    if (t < o) { rs[t] += rs[t + o]; rq[t] += rq[t + o]; }
    __syncthreads();
  }
  float mean = rs[0] * (1.f / 512.f);
  float var = fmaxf(rq[0] * (1.f / 512.f) - mean * mean, 0.f);
  float rinv = rsqrtf(var + 1e-5f);
  float o0 = (v0 - mean) * rinv * g[t] + bb[t];
  float o1 = (v1 - mean) * rinv * g[t + 256] + bb[t + 256];
  p[t] = o0; p[t + 256] = o1;
  pb[t] = f2b(o0); pb[t + 256] = f2b(o1);
}

// ---------- sparse block attention, MFMA version: one wave per (b, h, n) ----------
__global__ __launch_bounds__(64) void attnm_k(const u16* __restrict__ qkv, u16* __restrict__ av,
    const int* __restrict__ rnd, int S, int Sp, int nb)
{
  __shared__ __align__(16) u16 Vt[64 * 104];
  __shared__ __align__(16) u16 Pl[16 * 104];
  __shared__ int sJB[10], sVD[10];
  int t = threadIdx.x;
  int n = blockIdx.x % nb;
  int r1 = blockIdx.x / nb;
  int hh = r1 & 7, b = r1 >> 3;
  const u16* base = qkv + (size_t)b * Sp * 1536;
  int l15 = t & 15, quad = t >> 4;

  if (t < 10) {
    int jb, vd;
    if (t < 2) { jb = t; vd = 1; }
    else if (t < 7) {
      int w = n + t - 4;
      vd = (w >= 0 && w < nb) ? 1 : 0;
      jb = w < 0 ? 0 : (w > nb - 1 ? nb - 1 : w);
    } else { jb = rnd[n * 3 + t - 7]; vd = 1; }
    sJB[t] = jb; sVD[t] = vd;
  }
  {
    f32x4 zz = {0.f, 0.f, 0.f, 0.f};
    *(f32x4*)&Vt[t * 104 + 80] = zz;
    *(f32x4*)&Vt[t * 104 + 88] = zz;
    if (t < 16) {
      *(f32x4*)&Pl[t * 104 + 80] = zz;
      *(f32x4*)&Pl[t * 104 + 88] = zz;
    }
  }
  __syncthreads();

  short8 aq0, aq1;
  {
    const u16* qp = base + (size_t)(n * 8 + (l15 & 7)) * 1536 + hh * 64 + quad * 8;
    aq0 = *(const short8*)qp;
    aq1 = *(const short8*)(qp + 32);
  }

  f32x4 s[5];
  float okm[5];
  #pragma unroll
  for (int tile = 0; tile < 5; ++tile) {
    int kb = tile * 2 + (l15 >> 3);
    int tok = sJB[kb] * 8 + (l15 & 7);
    okm[tile] = (sVD[kb] && tok < S) ? 0.f : -3.0e38f;
    const u16* kp = base + (size_t)tok * 1536 + 512 + hh * 64 + quad * 8;
    short8 k0 = *(const short8*)kp;
    short8 k1 = *(const short8*)(kp + 32);
    f32x4 c = {0.f, 0.f, 0.f, 0.f};
    c = __builtin_amdgcn_mfma_f32_16x16x32_bf16(aq0, k0, c, 0, 0, 0);
    c = __builtin_amdgcn_mfma_f32_16x16x32_bf16(aq1, k1, c, 0, 0, 0);
    s[tile] = c;
  }

  u16 vreg[80];
  #pragma unroll
  for (int vt = 0; vt < 10; ++vt) {
    const u16* vp = base + (size_t)(sJB[vt] * 8) * 1536 + 1024 + hh * 64 + t;
    #pragma unroll
    for (int j = 0; j < 8; ++j) vreg[vt * 8 + j] = vp[(size_t)j * 1536];
  }

  f32x4 mx = {-3.0e38f, -3.0e38f, -3.0e38f, -3.0e38f};
  #pragma unroll
  for (int tile = 0; tile < 5; ++tile) {
    #pragma unroll
    for (int r = 0; r < 4; ++r) {
      float v = s[tile][r] * 0.125f + okm[tile];
      s[tile][r] = v;
      mx[r] = fmaxf(mx[r], v);
    }
  }
  #pragma unroll
  for (int off = 1; off < 16; off <<= 1) {
    #pragma unroll
    for (int r = 0; r < 4; ++r) mx[r] = fmaxf(mx[r], __shfl_xor(mx[r], off));
  }
  f32x4 sm = {0.f, 0.f, 0.f, 0.f};
  #pragma unroll
  for (int tile = 0; tile < 5; ++tile) {
    #pragma unroll
    for (int r = 0; r < 4; ++r) {
      float e = __expf(s[tile][r] - mx[r]);
      s[tile][r] = e;
      sm[r] += e;
    }
  }
  #pragma unroll
  for (int off = 1; off < 16; off <<= 1) {
    #pragma unroll
    for (int r = 0; r < 4; ++r) sm[r] += __shfl_xor(sm[r], off);
  }

  #pragma unroll
  for (int tile = 0; tile < 5; ++tile)
    #pragma unroll
    for (int r = 0; r < 4; ++r)
      Pl[(quad * 4 + r) * 104 + tile * 16 + l15] = f2b(s[tile][r]);

  #pragma unroll
  for (int vt = 0; vt < 10; ++vt) {
    short8 w;
    #pragma unroll
    for (int j = 0; j < 8; ++j) ((u16*)&w)[j] = (short)vreg[vt * 8 + j];
    *(short8*)&Vt[t * 104 + vt * 8] = w;
  }
  __syncthreads();

  f32x4 o[4];
  #pragma unroll
  for (int dn = 0; dn < 4; ++dn) o[dn] = (f32x4){0.f, 0.f, 0.f, 0.f};
  #pragma unroll
  for (int ks = 0; ks < 3; ++ks) {
    short8 ap = *(const short8*)&Pl[l15 * 104 + ks * 32 + quad * 8];
    #pragma unroll
    for (int dn = 0; dn < 4; ++dn) {
      short8 bv = *(const short8*)&Vt[(dn * 16 + l15) * 104 + ks * 32 + quad * 8];
      o[dn] = __builtin_amdgcn_mfma_f32_16x16x32_bf16(ap, bv, o[dn], 0, 0, 0);
    }
  }

  if (quad < 2) {
    #pragma unroll
    for (int r = 0; r < 4; ++r) {
      int qi = quad * 4 + r;
      float inv = 1.f / sm[r];
      u16* op = av + ((size_t)b * Sp + n * 8 + qi) * 512 + hh * 64 + l15;
      #pragma unroll
      for (int dn = 0; dn < 4; ++dn)
        op[dn * 16] = f2b(o[dn][r] * inv);
    }
  }
}

// ---------- VAE head ----------
__global__ __launch_bounds__(512) void head_k(const float* __restrict__ h,
    const float* __restrict__ Wm, const float* __restrict__ bm,
    const float* __restrict__ Wlv, const float* __restrict__ blv,
    const float* __restrict__ eps, float* __restrict__ z, float* out_elbo)
{
  __shared__ float red[512];
  int t = threadIdx.x;
  int b = t >> 4, i = t & 15;
  const float* p = h + (size_t)b * SPENC * 512;
  float am = bm[i], al = blv[i];
  for (int c = 0; c < 512; ++c) {
    float pv = p[c];
    am += pv * Wm[c * 16 + i];
    al += pv * Wlv[c * 16 + i];
  }
  z[t] = am + eps[t] * expf(0.5f * al);
  red[t] = -0.5f * (1.f + al - am * am - expf(al));
  __syncthreads();
  for (int o = 256; o > 0; o >>= 1) { if (t < o) red[t] += red[t + o]; __syncthreads(); }
  if (t == 0) out_elbo[0] = red[0] * (1.f / 32.f);
}

// ---------- seq ----------
__global__ __launch_bounds__(256) void seq_k(const float* __restrict__ z, const float* __restrict__ We,
    const float* __restrict__ be, float* __restrict__ seq)
{
  int gid = blockIdx.x * 256 + threadIdx.x;
  int b = gid >> 11, c = gid & 2047;
  float acc = be[c];
  #pragma unroll
  for (int i = 0; i < 16; ++i) acc += z[b * 16 + i] * We[i * 2048 + c];
  seq[gid] = acc;
}

// ---------- decoder init: h fp32 + hb bf16 ----------
__global__ __launch_bounds__(256) void decinit_k(const float* __restrict__ seq, const float* __restrict__ Wc,
    const float* __restrict__ bc, const float* __restrict__ emb, float* __restrict__ h, u16* __restrict__ hb)
{
  size_t gid = (size_t)blockIdx.x * 256 + threadIdx.x;
  int dd = (int)(gid & 511);
  size_t rs = gid >> 9;
  int s = (int)(rs & 1023);
  int b = (int)(rs >> 10);
  float v = seq[b * 2048 + s] * Wc[dd] + seq[b * 2048 + 1024 + s] * Wc[512 + dd]
          + bc[dd] + emb[(size_t)s * 512 + dd];
  h[gid] = v;
  hb[gid] = f2b(v);
}

// ---------- final ----------
__global__ __launch_bounds__(256) void final_k(const float* __restrict__ h, const float* __restrict__ Ws,
    const float* __restrict__ bs, float* __restrict__ out)
{
  int gid = blockIdx.x * 256 + threadIdx.x;
  int nn = gid & 15;
  int rs = gid >> 4;
  const float* p = h + (size_t)rs * 512;
  float acc = bs[nn];
  for (int c = 0; c < 512; ++c) acc += p[c] * Ws[c * 16 + nn];
  out[gid] = acc;
}

extern "C" void kernel_launch(void* const* d_in, const int* in_sizes, int n_in,
                              void* d_out, int out_size, void* d_ws, size_t ws_size,
                              hipStream_t stream) {
  float* out = (float*)d_out;
  (void)out_size; (void)ws_size;

  static const int EXP_DICT[30] = {
    524288, 512, 524800, 524288, 8192, 512, 7864320, 15360, 2621440, 5120,
    5120, 5120, 10485760, 20480, 10485760, 5120, 5120, 5120, 8192, 16,
    8192, 16, 32768, 2048, 1024, 512, 8192, 16, 387, 384 };
  bool dict_ok = (n_in == 30);
  if (dict_ok) for (int i = 0; i < 30; ++i) if (in_sizes[i] != EXP_DICT[i]) { dict_ok = false; break; }
  if (!dict_ok) { beacon_k<<<1, 64, 0, stream>>>(out); return; }

  const float* x      = (const float*)d_in[0];
  const float* eps    = (const float*)d_in[1];
  const float* emb_in = (const float*)d_in[2];
  const float* emb_out= (const float*)d_in[3];
  const float* W_data = (const float*)d_in[4];
  const float* b_data = (const float*)d_in[5];
  const float* Wqkv   = (const float*)d_in[6];
  const float* bqkv   = (const float*)d_in[7];
  const float* Wo     = (const float*)d_in[8];
  const float* bo     = (const float*)d_in[9];
  const float* ln1g   = (const float*)d_in[10];
  const float* ln1b   = (const float*)d_in[11];
  const float* W1     = (const float*)d_in[12];
  const float* b1     = (const float*)d_in[13];
  const float* W2     = (const float*)d_in[14];
  const float* b2     = (const float*)d_in[15];
  const float* ln2g   = (const float*)d_in[16];
  const float* ln2b   = (const float*)d_in[17];
  const float* Wm     = (const float*)d_in[18];
  const float* bm     = (const float*)d_in[19];
  const float* Wlv    = (const float*)d_in[20];
  const float* blv    = (const float*)d_in[21];
  const float* Wexp   = (const float*)d_in[22];
  const float* bexp   = (const float*)d_in[23];
  const float* Wconv  = (const float*)d_in[24];
  const float* bconv  = (const float*)d_in[25];
  const float* Wseq   = (const float*)d_in[26];
  const float* bseq   = (const float*)d_in[27];
  const int* rand_enc = (const int*)d_in[28];
  const int* rand_dec = (const int*)d_in[29];

  // ---- workspace carve (~194.5 MB; proven-safe envelope 203 MB) ----
  char* ws = (char*)d_ws;
  float* h     = (float*)ws;
  u16*   hb    = (u16*)(ws + 67633152);
  u16*   WTqkv = (u16*)(ws + 101449728);
  u16*   WTo   = (u16*)(ws + 117178368);
  u16*   WT1l  = (u16*)(ws + 122421248);
  u16*   WT2l  = (u16*)(ws + 124518400);
  u16*   qkvb  = (u16*)(ws + 126615552);
  u16*   avb   = (u16*)(ws + 126615552 + 50724864);
  u16*   ffnb  = (u16*)(ws + 126615552);             // union with qkvb+avb
  float* seqb  = (float*)(ws + 194248704);
  float* z     = (float*)(ws + 194510848);

  // ---- persistent weight transpose+convert (qkv, o for all 10 layers) ----
  tr_k<<<dim3(512 / 32, 1536 / 32, 10), 256, 0, stream>>>(Wqkv, WTqkv, 512, 1536);
  tr_k<<<dim3(512 / 32, 512 / 32, 10), 256, 0, stream>>>(Wo, WTo, 512, 512);

  // ===== encoder: M=33024; attention path in 2 chunks of 16 batches (Mc=16512) =====
  {
    const int M = MENC;
    embed_k<<<(M * 512) / 256, 256, 0, stream>>>(x, W_data, b_data, emb_in, h, hb);
    for (int i = 0; i < 5; ++i) {
      for (int bc = 0; bc < 2; ++bc) {
        size_t roff = (size_t)bc * 16 * SPENC * 512;
        const int Mc = 16 * SPENC;  // 16512
        const int ty = 129;         // 16512/128
        mgemm_k<u16, false, false, false><<<dim3(1536 / 256, ty, 1), 512, 0, stream>>>(
            hb + roff, WTqkv + (size_t)i * 512 * 1536, bqkv + (size_t)i * 1536, nullptr, qkvb, Mc, 1536, 512, 512, 512);
        attnm_k<<<16 * 8 * NBE, 64, 0, stream>>>(qkvb, avb, rand_enc, SENC, SPENC, NBE);
        // Wo: split-K=2, atomic into h (h pre-holds residual)
        mgemm_k<float, false, false, true><<<dim3(512 / 256, ty, 2), 512, 0, stream>>>(
            avb, WTo + (size_t)i * 512 * 512, bo + (size_t)i * 512, nullptr, h + roff, Mc, 512, 256, 512, 512);
      }
      ln_k<<<M, 256, 0, stream>>>(h, hb, ln1g + (size_t)i * 512, ln1b + (size_t)i * 512);
      // per-layer FFN weight transposes (WT1l/WT2l)
      tr_k<<<dim3(512 / 32, 2048 / 32, 1), 256, 0, stream>>>(W1 + (size_t)i * 512 * 2048, WT1l, 512, 2048);
      tr_k<<<dim3(2048 / 32, 512 / 32, 1), 256, 0, stream>>>(W2 + (size_t)i * 2048 * 512, WT2l, 2048, 512);
      for (int off = 0; off < M; off += 16512) {
        const int Mc = 16512;  // 33024 = 2 * 16512 exactly
        const int ty = 129;
        mgemm_k<u16, true, false, false><<<dim3(2048 / 256, ty, 1), 512, 0, stream>>>(
            hb + (size_t)off * 512, WT1l, b1 + (size_t)i * 2048, nullptr, ffnb, Mc, 2048, 512, 512, 512);
        // W2: split-K=2 (Kc=1024), atomic into h (h pre-holds post-ln1 residual)
        mgemm_k<float, false, false, true><<<dim3(512 / 256, ty, 2), 512, 0, stream>>>(
            ffnb, WT2l, b2 + (size_t)i * 512, nullptr, h + (size_t)off * 512, Mc, 512, 1024, 2048, 2048);
      }
      ln_k<<<M, 256, 0, stream>>>(h, hb, ln2g + (size_t)i * 512, ln2b + (size_t)i * 512);
    }
  }

  // ===== VAE head =====
  head_k<<<1, 512, 0, stream>>>(h, Wm, bm, Wlv, blv, eps, z, out + 524288);
  seq_k<<<256, 256, 0, stream>>>(z, Wexp, bexp, seqb);
  decinit_k<<<(MDEC * 512) / 256, 256, 0, stream>>>(seqb, Wconv, bconv, emb_out, h, hb);

  // ===== decoder: M=32768; attention path in 2 chunks of 16 batches (Mc=16384) =====
  {
    const int M = MDEC;
    for (int i = 5; i < 10; ++i) {
      for (int bc = 0; bc < 2; ++bc) {
        size_t roff = (size_t)bc * 16 * SDEC * 512;
        const int Mc = 16 * SDEC;  // 16384
        const int ty = 128;
        mgemm_k<u16, false, false, false><<<dim3(1536 / 256, ty, 1), 512, 0, stream>>>(
            hb + roff, WTqkv + (size_t)i * 512 * 1536, bqkv + (size_t)i * 1536, nullptr, qkvb, Mc, 1536, 512, 512, 512);
        attnm_k<<<16 * 8 * NBD, 64, 0, stream>>>(qkvb, avb, rand_dec, SDEC, SDEC, NBD);
        mgemm_k<float, false, false, true><<<dim3(512 / 256, ty, 2), 512, 0, stream>>>(
            avb, WTo + (size_t)i * 512 * 512, bo + (size_t)i * 512, nullptr, h + roff, Mc, 512, 256, 512, 512);
      }
      ln_k<<<M, 256, 0, stream>>>(h, hb, ln1g + (size_t)i * 512, ln1b + (size_t)i * 512);
      tr_k<<<dim3(512 / 32, 2048 / 32, 1), 256, 0, stream>>>(W1 + (size_t)i * 512 * 2048, WT1l, 512, 2048);
      tr_k<<<dim3(2048 / 32, 512 / 32, 1), 256, 0, stream>>>(W2 + (size_t)i * 2048 * 512, WT2l, 2048, 512);
      for (int off = 0; off < M; off += 16384) {
        const int Mc = 16384;
        const int ty = 128;
        mgemm_k<u16, true, false, false><<<dim3(2048 / 256, ty, 1), 512, 0, stream>>>(
            hb + (size_t)off * 512, WT1l, b1 + (size_t)i * 2048, nullptr, ffnb, Mc, 2048, 512, 512, 512);
        mgemm_k<float, false, false, true><<<dim3(512 / 256, ty, 2), 512, 0, stream>>>(
            ffnb, WT2l, b2 + (size_t)i * 512, nullptr, h + (size_t)off * 512, Mc, 512, 1024, 2048, 2048);
      }
      ln_k<<<M, 256, 0, stream>>>(h, hb, ln2g + (size_t)i * 512, ln2b + (size_t)i * 512);
    }
  }

  // ===== output =====
  final_k<<<524288 / 256, 256, 0, stream>>>(h, Wseq, bseq, out);
}

// Round 9
// 6140.400 us; speedup vs baseline: 1.1785x; 1.0949x over previous
//
#include <hip/hip_runtime.h>

typedef unsigned short u16;
typedef __attribute__((ext_vector_type(8))) short short8;
typedef __attribute__((ext_vector_type(4))) float f32x4;

__device__ __forceinline__ float b2f(u16 h) {
  union { unsigned int u; float f; } v; v.u = ((unsigned int)h) << 16; return v.f;
}
__device__ __forceinline__ u16 f2b(float f) {
  union { float f; unsigned int u; } v; v.f = f;
  return (u16)((v.u + 0x7fffu + ((v.u >> 16) & 1u)) >> 16);
}

// async global->LDS, 16B per lane; dst must be wave-base + lane*16 (m97 pattern)
__device__ __forceinline__ void gload16(const u16* g, u16* l) {
  __builtin_amdgcn_global_load_lds(
      (const __attribute__((address_space(1))) void*)g,
      (__attribute__((address_space(3))) void*)l, 16, 0, 0);
}

#define SENC 1025
#define SPENC 1032
#define NBE 129
#define SDEC 1024
#define NBD 128
#define BATCH 32
#define MENC (BATCH * SPENC)  /* 33024 */
#define MDEC (BATCH * SDEC)   /* 32768 */

// ---------- beacon ----------
__global__ void beacon_k(float* out) { if (threadIdx.x == 0) out[0] = 1000.0f; }

// ---------- weight transpose + bf16 convert: WT[n][k] = bf16(W[k][n]) ----------
__global__ __launch_bounds__(256) void tr_k(const float* __restrict__ W, u16* __restrict__ WT, int K, int N)
{
  __shared__ float sm[32][33];
  int k0 = blockIdx.x * 32, n0 = blockIdx.y * 32;
  const float* Wz = W + (size_t)blockIdx.z * K * N;
  u16* WTz = WT + (size_t)blockIdx.z * K * N;
  int r = threadIdx.x >> 3, c0 = (threadIdx.x & 7) * 4;
  float4 v = *(const float4*)&Wz[(size_t)(k0 + r) * N + n0 + c0];
  sm[r][c0] = v.x; sm[r][c0 + 1] = v.y; sm[r][c0 + 2] = v.z; sm[r][c0 + 3] = v.w;
  __syncthreads();
  ushort4 u;
  u.x = f2b(sm[c0][r]); u.y = f2b(sm[c0 + 1][r]); u.z = f2b(sm[c0 + 2][r]); u.w = f2b(sm[c0 + 3][r]);
  *(ushort4*)&WTz[(size_t)(n0 + r) * K + k0 + c0] = u;
}

// ---------- embed: h fp32 + hb bf16 ----------
__global__ __launch_bounds__(256) void embed_k(const float* __restrict__ x, const float* __restrict__ Wd,
    const float* __restrict__ bd, const float* __restrict__ emb, float* __restrict__ h, u16* __restrict__ hb)
{
  size_t gid = (size_t)blockIdx.x * 256 + threadIdx.x;  // MENC*512
  int dd = (int)(gid & 511);
  size_t rs = gid >> 9;
  int s = (int)(rs % SPENC);
  int b = (int)(rs / SPENC);
  float v;
  if (s == 0) {
    v = emb[dd];
  } else if (s < SENC) {
    float acc = bd[dd];
    const float* xr = x + ((size_t)b * 1024 + (s - 1)) * 16;
    #pragma unroll
    for (int j = 0; j < 16; ++j) acc += xr[j] * Wd[j * 512 + dd];
    v = acc + emb[(size_t)s * 512 + dd];
  } else {
    v = 0.f;
  }
  h[gid] = v;
  hb[gid] = f2b(v);
}

// ---------- MFMA bf16 GEMM, 128x256 tile, 512 threads (8 waves) ----------
// Triple-buffered LDS + counted vmcnt; output always bf16 (u16) + bias (+ReLU).
// No split-K, no atomics: C[M,N] = A[M,K] @ WT[N,K]^T + bias.
// LDS chunk (16B = 8 bf16): logical k-chunk c of row r stored at slot r*4 + (c ^ ((r>>1)&3)).
template<bool RELU>
__global__ __launch_bounds__(512) void mgemm_k(const u16* __restrict__ A, const u16* __restrict__ WT,
    const float* __restrict__ bias, u16* __restrict__ C,
    int M, int N, int Kc, int lda, int ldb)
{
  __shared__ __align__(16) u16 sA[3][128 * 32];   // 24 KB
  __shared__ __align__(16) u16 sB[3][256 * 32];   // 48 KB
  int t = threadIdx.x;

  // bijective XCD-aware remap of the flattened (x,y) id
  int gx = gridDim.x;
  int nwg = gx * gridDim.y;
  int flat = blockIdx.y * gx + blockIdx.x;
  int q = nwg >> 3, rr = nwg & 7;
  int xcd = flat & 7, idx = flat >> 3;
  int swz = (xcd < rr ? xcd * (q + 1) : rr * (q + 1) + (xcd - rr) * q) + idx;
  int bx = swz % gx, by = swz / gx;

  int n0 = bx * 256, m0 = by * 128;
  int lane = t & 63, wave = t >> 6;            // 8 waves: 2M x 4N
  int wm = (wave >> 2) * 64, wn = (wave & 3) * 64;
  int quad = lane >> 4, l15 = lane & 15;

  // staging: A 1 issue (512 chunks), B 2 issues (1024 chunks); chunk ch -> row ch>>2, slot ch&3
  int rA = t >> 2, sc = t & 3;
  int cA = sc ^ ((rA >> 1) & 3);
  int raA = m0 + rA; raA = raA < M ? raA : M - 1;
  const u16* gA  = A  + (size_t)raA * lda + cA * 8;
  const u16* gB0 = WT + (size_t)(n0 + rA) * ldb + cA * 8;       // rows 0..127
  const u16* gB1 = WT + (size_t)(n0 + 128 + rA) * ldb + cA * 8; // rows 128..255 (same xor)

  f32x4 acc[4][4];
  #pragma unroll
  for (int i = 0; i < 4; ++i)
    #pragma unroll
    for (int j = 0; j < 4; ++j) acc[i][j] = (f32x4){0.f, 0.f, 0.f, 0.f};

  const int nt = Kc >> 5;
  // prologue: stage tile 0 -> buf0, tile 1 -> buf1 (6 loads in flight per wave)
  gload16(gA,      &sA[0][t * 8]);
  gload16(gB0,     &sB[0][t * 8]);
  gload16(gB1,     &sB[0][(512 + t) * 8]);
  gload16(gA + 32, &sA[1][t * 8]);
  gload16(gB0 + 32,&sB[1][t * 8]);
  gload16(gB1 + 32,&sB[1][(512 + t) * 8]);

  int cur = 0;
  for (int tt = 0; tt < nt; ++tt) {
    if (tt < nt - 1) {
      asm volatile("s_waitcnt vmcnt(3)" ::: "memory");   // tile tt landed; tile tt+1 in flight
    } else {
      asm volatile("s_waitcnt vmcnt(0)" ::: "memory");
    }
    __builtin_amdgcn_s_barrier();
    asm volatile("" ::: "memory");
    if (tt + 2 < nt) {
      int k0 = (tt + 2) << 5;
      int nb = tt + 2; nb -= (nb / 3) * 3;               // (tt+2) % 3
      gload16(gA + k0,  &sA[nb][t * 8]);
      gload16(gB0 + k0, &sB[nb][t * 8]);
      gload16(gB1 + k0, &sB[nb][(512 + t) * 8]);
    }
    short8 af[4], bf[4];
    #pragma unroll
    for (int i = 0; i < 4; ++i) {
      int ra = wm + i * 16 + l15;
      af[i] = *(const short8*)&sA[cur][ra * 32 + (quad ^ ((ra >> 1) & 3)) * 8];
    }
    #pragma unroll
    for (int j = 0; j < 4; ++j) {
      int rb = wn + j * 16 + l15;
      bf[j] = *(const short8*)&sB[cur][rb * 32 + (quad ^ ((rb >> 1) & 3)) * 8];
    }
    __builtin_amdgcn_s_setprio(1);
    #pragma unroll
    for (int i = 0; i < 4; ++i)
      #pragma unroll
      for (int j = 0; j < 4; ++j)
        acc[i][j] = __builtin_amdgcn_mfma_f32_16x16x32_bf16(af[i], bf[j], acc[i][j], 0, 0, 0);
    __builtin_amdgcn_s_setprio(0);
    cur = (cur == 2) ? 0 : cur + 1;
  }

  // epilogue: D row = quad*4+reg (m), col = lane&15 (n)  [m89-verified]
  #pragma unroll
  for (int i = 0; i < 4; ++i) {
    int mBase = m0 + wm + i * 16 + quad * 4;
    #pragma unroll
    for (int r = 0; r < 4; ++r) {
      int m = mBase + r;
      if (m < M) {
        #pragma unroll
        for (int j = 0; j < 4; ++j) {
          int n = n0 + wn + j * 16 + l15;
          float v = acc[i][j][r] + bias[n];
          if (RELU) v = fmaxf(v, 0.f);
          C[(size_t)m * N + n] = f2b(v);
        }
      }
    }
  }
}

// ---------- fused residual + LayerNorm: h = LN(h + tmp); emits bf16 shadow ----------
// tmp is the bf16 GEMM output (bias already added). One block per row, shfl reduce.
__global__ __launch_bounds__(256) void lnf_k(float* __restrict__ h, const u16* __restrict__ tmp,
    u16* __restrict__ hb, const float* __restrict__ g, const float* __restrict__ bb)
{
  __shared__ float ls[4], lq[4];
  int t = threadIdx.x;
  float* p = h + (size_t)blockIdx.x * 512;
  const u16* tp = tmp + (size_t)blockIdx.x * 512;
  u16* pb = hb + (size_t)blockIdx.x * 512;
  float2 hv = *(const float2*)&p[2 * t];
  ushort2 tv = *(const ushort2*)&tp[2 * t];
  float v0 = hv.x + b2f(tv.x);
  float v1 = hv.y + b2f(tv.y);
  float s = v0 + v1, qq = v0 * v0 + v1 * v1;
  #pragma unroll
  for (int off = 1; off < 64; off <<= 1) {
    s += __shfl_xor(s, off);
    qq += __shfl_xor(qq, off);
  }
  if ((t & 63) == 0) { ls[t >> 6] = s; lq[t >> 6] = qq; }
  __syncthreads();
  s = ls[0] + ls[1] + ls[2] + ls[3];
  qq = lq[0] + lq[1] + lq[2] + lq[3];
  float mean = s * (1.f / 512.f);
  float var = fmaxf(qq * (1.f / 512.f) - mean * mean, 0.f);
  float rinv = rsqrtf(var + 1e-5f);
  float o0 = (v0 - mean) * rinv * g[2 * t] + bb[2 * t];
  float o1 = (v1 - mean) * rinv * g[2 * t + 1] + bb[2 * t + 1];
  *(float2*)&p[2 * t] = make_float2(o0, o1);
  ushort2 ob; ob.x = f2b(o0); ob.y = f2b(o1);
  *(ushort2*)&pb[2 * t] = ob;
}

// ---------- sparse block attention, MFMA version: one wave per (b, h, n) ----------
__global__ __launch_bounds__(64) void attnm_k(const u16* __restrict__ qkv, u16* __restrict__ av,
    const int* __restrict__ rnd, int S, int Sp, int nb)
{
  __shared__ __align__(16) u16 Vt[64 * 104];
  __shared__ __align__(16) u16 Pl[16 * 104];
  __shared__ int sJB[10], sVD[10];
  int t = threadIdx.x;
  int n = blockIdx.x % nb;
  int r1 = blockIdx.x / nb;
  int hh = r1 & 7, b = r1 >> 3;
  const u16* base = qkv + (size_t)b * Sp * 1536;
  int l15 = t & 15, quad = t >> 4;

  if (t < 10) {
    int jb, vd;
    if (t < 2) { jb = t; vd = 1; }
    else if (t < 7) {
      int w = n + t - 4;
      vd = (w >= 0 && w < nb) ? 1 : 0;
      jb = w < 0 ? 0 : (w > nb - 1 ? nb - 1 : w);
    } else { jb = rnd[n * 3 + t - 7]; vd = 1; }
    sJB[t] = jb; sVD[t] = vd;
  }
  {
    f32x4 zz = {0.f, 0.f, 0.f, 0.f};
    *(f32x4*)&Vt[t * 104 + 80] = zz;
    *(f32x4*)&Vt[t * 104 + 88] = zz;
    if (t < 16) {
      *(f32x4*)&Pl[t * 104 + 80] = zz;
      *(f32x4*)&Pl[t * 104 + 88] = zz;
    }
  }
  __syncthreads();

  short8 aq0, aq1;
  {
    const u16* qp = base + (size_t)(n * 8 + (l15 & 7)) * 1536 + hh * 64 + quad * 8;
    aq0 = *(const short8*)qp;
    aq1 = *(const short8*)(qp + 32);
  }

  f32x4 s[5];
  float okm[5];
  #pragma unroll
  for (int tile = 0; tile < 5; ++tile) {
    int kb = tile * 2 + (l15 >> 3);
    int tok = sJB[kb] * 8 + (l15 & 7);
    okm[tile] = (sVD[kb] && tok < S) ? 0.f : -3.0e38f;
    const u16* kp = base + (size_t)tok * 1536 + 512 + hh * 64 + quad * 8;
    short8 k0 = *(const short8*)kp;
    short8 k1 = *(const short8*)(kp + 32);
    f32x4 c = {0.f, 0.f, 0.f, 0.f};
    c = __builtin_amdgcn_mfma_f32_16x16x32_bf16(aq0, k0, c, 0, 0, 0);
    c = __builtin_amdgcn_mfma_f32_16x16x32_bf16(aq1, k1, c, 0, 0, 0);
    s[tile] = c;
  }

  u16 vreg[80];
  #pragma unroll
  for (int vt = 0; vt < 10; ++vt) {
    const u16* vp = base + (size_t)(sJB[vt] * 8) * 1536 + 1024 + hh * 64 + t;
    #pragma unroll
    for (int j = 0; j < 8; ++j) vreg[vt * 8 + j] = vp[(size_t)j * 1536];
  }

  f32x4 mx = {-3.0e38f, -3.0e38f, -3.0e38f, -3.0e38f};
  #pragma unroll
  for (int tile = 0; tile < 5; ++tile) {
    #pragma unroll
    for (int r = 0; r < 4; ++r) {
      float v = s[tile][r] * 0.125f + okm[tile];
      s[tile][r] = v;
      mx[r] = fmaxf(mx[r], v);
    }
  }
  #pragma unroll
  for (int off = 1; off < 16; off <<= 1) {
    #pragma unroll
    for (int r = 0; r < 4; ++r) mx[r] = fmaxf(mx[r], __shfl_xor(mx[r], off));
  }
  f32x4 sm = {0.f, 0.f, 0.f, 0.f};
  #pragma unroll
  for (int tile = 0; tile < 5; ++tile) {
    #pragma unroll
    for (int r = 0; r < 4; ++r) {
      float e = __expf(s[tile][r] - mx[r]);
      s[tile][r] = e;
      sm[r] += e;
    }
  }
  #pragma unroll
  for (int off = 1; off < 16; off <<= 1) {
    #pragma unroll
    for (int r = 0; r < 4; ++r) sm[r] += __shfl_xor(sm[r], off);
  }

  #pragma unroll
  for (int tile = 0; tile < 5; ++tile)
    #pragma unroll
    for (int r = 0; r < 4; ++r)
      Pl[(quad * 4 + r) * 104 + tile * 16 + l15] = f2b(s[tile][r]);

  #pragma unroll
  for (int vt = 0; vt < 10; ++vt) {
    short8 w;
    #pragma unroll
    for (int j = 0; j < 8; ++j) ((u16*)&w)[j] = (short)vreg[vt * 8 + j];
    *(short8*)&Vt[t * 104 + vt * 8] = w;
  }
  __syncthreads();

  f32x4 o[4];
  #pragma unroll
  for (int dn = 0; dn < 4; ++dn) o[dn] = (f32x4){0.f, 0.f, 0.f, 0.f};
  #pragma unroll
  for (int ks = 0; ks < 3; ++ks) {
    short8 ap = *(const short8*)&Pl[l15 * 104 + ks * 32 + quad * 8];
    #pragma unroll
    for (int dn = 0; dn < 4; ++dn) {
      short8 bv = *(const short8*)&Vt[(dn * 16 + l15) * 104 + ks * 32 + quad * 8];
      o[dn] = __builtin_amdgcn_mfma_f32_16x16x32_bf16(ap, bv, o[dn], 0, 0, 0);
    }
  }

  if (quad < 2) {
    #pragma unroll
    for (int r = 0; r < 4; ++r) {
      int qi = quad * 4 + r;
      float inv = 1.f / sm[r];
      u16* op = av + ((size_t)b * Sp + n * 8 + qi) * 512 + hh * 64 + l15;
      #pragma unroll
      for (int dn = 0; dn < 4; ++dn)
        op[dn * 16] = f2b(o[dn][r] * inv);
    }
  }
}

// ---------- VAE head ----------
__global__ __launch_bounds__(512) void head_k(const float* __restrict__ h,
    const float* __restrict__ Wm, const float* __restrict__ bm,
    const float* __restrict__ Wlv, const float* __restrict__ blv,
    const float* __restrict__ eps, float* __restrict__ z, float* out_elbo)
{
  __shared__ float red[512];
  int t = threadIdx.x;
  int b = t >> 4, i = t & 15;
  const float* p = h + (size_t)b * SPENC * 512;
  float am = bm[i], al = blv[i];
  for (int c = 0; c < 512; ++c) {
    float pv = p[c];
    am += pv * Wm[c * 16 + i];
    al += pv * Wlv[c * 16 + i];
  }
  z[t] = am + eps[t] * expf(0.5f * al);
  red[t] = -0.5f * (1.f + al - am * am - expf(al));
  __syncthreads();
  for (int o = 256; o > 0; o >>= 1) { if (t < o) red[t] += red[t + o]; __syncthreads(); }
  if (t == 0) out_elbo[0] = red[0] * (1.f / 32.f);
}

// ---------- seq ----------
__global__ __launch_bounds__(256) void seq_k(const float* __restrict__ z, const float* __restrict__ We,
    const float* __restrict__ be, float* __restrict__ seq)
{
  int gid = blockIdx.x * 256 + threadIdx.x;
  int b = gid >> 11, c = gid & 2047;
  float acc = be[c];
  #pragma unroll
  for (int i = 0; i < 16; ++i) acc += z[b * 16 + i] * We[i * 2048 + c];
  seq[gid] = acc;
}

// ---------- decoder init: h fp32 + hb bf16 ----------
__global__ __launch_bounds__(256) void decinit_k(const float* __restrict__ seq, const float* __restrict__ Wc,
    const float* __restrict__ bc, const float* __restrict__ emb, float* __restrict__ h, u16* __restrict__ hb)
{
  size_t gid = (size_t)blockIdx.x * 256 + threadIdx.x;
  int dd = (int)(gid & 511);
  size_t rs = gid >> 9;
  int s = (int)(rs & 1023);
  int b = (int)(rs >> 10);
  float v = seq[b * 2048 + s] * Wc[dd] + seq[b * 2048 + 1024 + s] * Wc[512 + dd]
          + bc[dd] + emb[(size_t)s * 512 + dd];
  h[gid] = v;
  hb[gid] = f2b(v);
}

// ---------- final ----------
__global__ __launch_bounds__(256) void final_k(const float* __restrict__ h, const float* __restrict__ Ws,
    const float* __restrict__ bs, float* __restrict__ out)
{
  int gid = blockIdx.x * 256 + threadIdx.x;
  int nn = gid & 15;
  int rs = gid >> 4;
  const float* p = h + (size_t)rs * 512;
  float acc = bs[nn];
  for (int c = 0; c < 512; ++c) acc += p[c] * Ws[c * 16 + nn];
  out[gid] = acc;
}

extern "C" void kernel_launch(void* const* d_in, const int* in_sizes, int n_in,
                              void* d_out, int out_size, void* d_ws, size_t ws_size,
                              hipStream_t stream) {
  float* out = (float*)d_out;
  (void)out_size; (void)ws_size;

  static const int EXP_DICT[30] = {
    524288, 512, 524800, 524288, 8192, 512, 7864320, 15360, 2621440, 5120,
    5120, 5120, 10485760, 20480, 10485760, 5120, 5120, 5120, 8192, 16,
    8192, 16, 32768, 2048, 1024, 512, 8192, 16, 387, 384 };
  bool dict_ok = (n_in == 30);
  if (dict_ok) for (int i = 0; i < 30; ++i) if (in_sizes[i] != EXP_DICT[i]) { dict_ok = false; break; }
  if (!dict_ok) { beacon_k<<<1, 64, 0, stream>>>(out); return; }

  const float* x      = (const float*)d_in[0];
  const float* eps    = (const float*)d_in[1];
  const float* emb_in = (const float*)d_in[2];
  const float* emb_out= (const float*)d_in[3];
  const float* W_data = (const float*)d_in[4];
  const float* b_data = (const float*)d_in[5];
  const float* Wqkv   = (const float*)d_in[6];
  const float* bqkv   = (const float*)d_in[7];
  const float* Wo     = (const float*)d_in[8];
  const float* bo     = (const float*)d_in[9];
  const float* ln1g   = (const float*)d_in[10];
  const float* ln1b   = (const float*)d_in[11];
  const float* W1     = (const float*)d_in[12];
  const float* b1     = (const float*)d_in[13];
  const float* W2     = (const float*)d_in[14];
  const float* b2     = (const float*)d_in[15];
  const float* ln2g   = (const float*)d_in[16];
  const float* ln2b   = (const float*)d_in[17];
  const float* Wm     = (const float*)d_in[18];
  const float* bm     = (const float*)d_in[19];
  const float* Wlv    = (const float*)d_in[20];
  const float* blv    = (const float*)d_in[21];
  const float* Wexp   = (const float*)d_in[22];
  const float* bexp   = (const float*)d_in[23];
  const float* Wconv  = (const float*)d_in[24];
  const float* bconv  = (const float*)d_in[25];
  const float* Wseq   = (const float*)d_in[26];
  const float* bseq   = (const float*)d_in[27];
  const int* rand_enc = (const int*)d_in[28];
  const int* rand_dec = (const int*)d_in[29];

  // ---- workspace carve (~194.5 MB; proven-safe envelope 203 MB) ----
  // union region U = [126615552, 194248704):
  //   attn phase: qkvb (50.7 MB) + avb (16.9 MB)
  //   Wo phase:   tmpo = U (<=33.8 MB; qkvb dead after attn)
  //   FFN phase:  ffnb = U (<=45.1 MB, Mc<=11008) + tmpF = U+45088768 (<=11.3 MB)
  char* ws = (char*)d_ws;
  float* h     = (float*)ws;
  u16*   hb    = (u16*)(ws + 67633152);
  u16*   WTqkv = (u16*)(ws + 101449728);
  u16*   WTo   = (u16*)(ws + 117178368);
  u16*   WT1l  = (u16*)(ws + 122421248);
  u16*   WT2l  = (u16*)(ws + 124518400);
  u16*   qkvb  = (u16*)(ws + 126615552);
  u16*   avb   = (u16*)(ws + 126615552 + 50724864);
  u16*   tmpo  = (u16*)(ws + 126615552);             // Wo-phase temp (union reuse)
  u16*   ffnb  = (u16*)(ws + 126615552);             // FFN activations (union reuse)
  u16*   tmpF  = (u16*)(ws + 126615552 + 45088768);  // W2 temp (after ffnb)
  float* seqb  = (float*)(ws + 194248704);
  float* z     = (float*)(ws + 194510848);

  // ---- persistent weight transpose+convert (qkv, o for all 10 layers) ----
  tr_k<<<dim3(512 / 32, 1536 / 32, 10), 256, 0, stream>>>(Wqkv, WTqkv, 512, 1536);
  tr_k<<<dim3(512 / 32, 512 / 32, 10), 256, 0, stream>>>(Wo, WTo, 512, 512);

  // ===== encoder: M=33024 =====
  {
    const int M = MENC;
    embed_k<<<(M * 512) / 256, 256, 0, stream>>>(x, W_data, b_data, emb_in, h, hb);
    for (int i = 0; i < 5; ++i) {
      // attention path: 2 chunks of 16 batches (Mc=16512)
      for (int bc = 0; bc < 2; ++bc) {
        size_t roff = (size_t)bc * 16 * SPENC * 512;
        const int Mc = 16 * SPENC;  // 16512
        const int ty = 129;         // 16512/128
        mgemm_k<false><<<dim3(6, ty), 512, 0, stream>>>(
            hb + roff, WTqkv + (size_t)i * 512 * 1536, bqkv + (size_t)i * 1536, qkvb, Mc, 1536, 512, 512, 512);
        attnm_k<<<16 * 8 * NBE, 64, 0, stream>>>(qkvb, avb, rand_enc, SENC, SPENC, NBE);
        mgemm_k<false><<<dim3(2, ty), 512, 0, stream>>>(
            avb, WTo + (size_t)i * 512 * 512, bo + (size_t)i * 512, tmpo, Mc, 512, 512, 512, 512);
        lnf_k<<<Mc, 256, 0, stream>>>(h + roff, tmpo, hb + roff, ln1g + (size_t)i * 512, ln1b + (size_t)i * 512);
      }
      // per-layer FFN weight transposes
      tr_k<<<dim3(512 / 32, 2048 / 32, 1), 256, 0, stream>>>(W1 + (size_t)i * 512 * 2048, WT1l, 512, 2048);
      tr_k<<<dim3(2048 / 32, 512 / 32, 1), 256, 0, stream>>>(W2 + (size_t)i * 2048 * 512, WT2l, 2048, 512);
      // FFN: 3 chunks of 11008 rows (33024 = 3*11008)
      for (int cc = 0; cc < 3; ++cc) {
        size_t off = (size_t)cc * 11008;
        const int Mc = 11008;
        const int ty = 86;  // 11008/128
        mgemm_k<true><<<dim3(8, ty), 512, 0, stream>>>(
            hb + off * 512, WT1l, b1 + (size_t)i * 2048, ffnb, Mc, 2048, 512, 512, 512);
        mgemm_k<false><<<dim3(2, ty), 512, 0, stream>>>(
            ffnb, WT2l, b2 + (size_t)i * 512, tmpF, Mc, 512, 2048, 2048, 2048);
        lnf_k<<<Mc, 256, 0, stream>>>(h + off * 512, tmpF, hb + off * 512, ln2g + (size_t)i * 512, ln2b + (size_t)i * 512);
      }
    }
  }

  // ===== VAE head =====
  head_k<<<1, 512, 0, stream>>>(h, Wm, bm, Wlv, blv, eps, z, out + 524288);
  seq_k<<<256, 256, 0, stream>>>(z, Wexp, bexp, seqb);
  decinit_k<<<(MDEC * 512) / 256, 256, 0, stream>>>(seqb, Wconv, bconv, emb_out, h, hb);

  // ===== decoder: M=32768 =====
  {
    for (int i = 5; i < 10; ++i) {
      for (int bc = 0; bc < 2; ++bc) {
        size_t roff = (size_t)bc * 16 * SDEC * 512;
        const int Mc = 16 * SDEC;  // 16384
        const int ty = 128;
        mgemm_k<false><<<dim3(6, ty), 512, 0, stream>>>(
            hb + roff, WTqkv + (size_t)i * 512 * 1536, bqkv + (size_t)i * 1536, qkvb, Mc, 1536, 512, 512, 512);
        attnm_k<<<16 * 8 * NBD, 64, 0, stream>>>(qkvb, avb, rand_dec, SDEC, SDEC, NBD);
        mgemm_k<false><<<dim3(2, ty), 512, 0, stream>>>(
            avb, WTo + (size_t)i * 512 * 512, bo + (size_t)i * 512, tmpo, Mc, 512, 512, 512, 512);
        lnf_k<<<Mc, 256, 0, stream>>>(h + roff, tmpo, hb + roff, ln1g + (size_t)i * 512, ln1b + (size_t)i * 512);
      }
      tr_k<<<dim3(512 / 32, 2048 / 32, 1), 256, 0, stream>>>(W1 + (size_t)i * 512 * 2048, WT1l, 512, 2048);
      tr_k<<<dim3(2048 / 32, 512 / 32, 1), 256, 0, stream>>>(W2 + (size_t)i * 2048 * 512, WT2l, 2048, 512);
      // FFN: chunks 11008, 11008, 10752 (32768 total)
      static const int DOFF[3] = {0, 11008, 22016};
      static const int DMC[3]  = {11008, 11008, 10752};
      for (int cc = 0; cc < 3; ++cc) {
        size_t off = (size_t)DOFF[cc];
        const int Mc = DMC[cc];
        const int ty = Mc / 128;  // 86, 86, 84
        mgemm_k<true><<<dim3(8, ty), 512, 0, stream>>>(
            hb + off * 512, WT1l, b1 + (size_t)i * 2048, ffnb, Mc, 2048, 512, 512, 512);
        mgemm_k<false><<<dim3(2, ty), 512, 0, stream>>>(
            ffnb, WT2l, b2 + (size_t)i * 512, tmpF, Mc, 512, 2048, 2048, 2048);
        lnf_k<<<Mc, 256, 0, stream>>>(h + off * 512, tmpF, hb + off * 512, ln2g + (size_t)i * 512, ln2b + (size_t)i * 512);
      }
    }
  }

  // ===== output =====
  final_k<<<524288 / 256, 256, 0, stream>>>(h, Wseq, bseq, out);
}

// Round 10
// 6091.933 us; speedup vs baseline: 1.1879x; 1.0080x over previous
//
#include <hip/hip_runtime.h>

typedef unsigned short u16;
typedef __attribute__((ext_vector_type(8))) short short8;
typedef __attribute__((ext_vector_type(4))) float f32x4;

__device__ __forceinline__ float b2f(u16 h) {
  union { unsigned int u; float f; } v; v.u = ((unsigned int)h) << 16; return v.f;
}
__device__ __forceinline__ u16 f2b(float f) {
  union { float f; unsigned int u; } v; v.f = f;
  return (u16)((v.u + 0x7fffu + ((v.u >> 16) & 1u)) >> 16);
}

// async global->LDS, 16B per lane; dst must be wave-base + lane*16 (m97 pattern)
__device__ __forceinline__ void gload16(const u16* g, u16* l) {
  __builtin_amdgcn_global_load_lds(
      (const __attribute__((address_space(1))) void*)g,
      (__attribute__((address_space(3))) void*)l, 16, 0, 0);
}

#define SENC 1025
#define SPENC 1032
#define NBE 129
#define SDEC 1024
#define NBD 128
#define BATCH 32
#define MENC (BATCH * SPENC)  /* 33024 */
#define MDEC (BATCH * SDEC)   /* 32768 */

// ---------- beacon ----------
__global__ void beacon_k(float* out) { if (threadIdx.x == 0) out[0] = 1000.0f; }

// ---------- weight transpose + bf16 convert: WT[n][k] = bf16(W[k][n]) ----------
__global__ __launch_bounds__(256) void tr_k(const float* __restrict__ W, u16* __restrict__ WT, int K, int N)
{
  __shared__ float sm[32][33];
  int k0 = blockIdx.x * 32, n0 = blockIdx.y * 32;
  const float* Wz = W + (size_t)blockIdx.z * K * N;
  u16* WTz = WT + (size_t)blockIdx.z * K * N;
  int r = threadIdx.x >> 3, c0 = (threadIdx.x & 7) * 4;
  float4 v = *(const float4*)&Wz[(size_t)(k0 + r) * N + n0 + c0];
  sm[r][c0] = v.x; sm[r][c0 + 1] = v.y; sm[r][c0 + 2] = v.z; sm[r][c0 + 3] = v.w;
  __syncthreads();
  ushort4 u;
  u.x = f2b(sm[c0][r]); u.y = f2b(sm[c0 + 1][r]); u.z = f2b(sm[c0 + 2][r]); u.w = f2b(sm[c0 + 3][r]);
  *(ushort4*)&WTz[(size_t)(n0 + r) * K + k0 + c0] = u;
}

// ---------- embed: h fp32 + hb bf16 ----------
__global__ __launch_bounds__(256) void embed_k(const float* __restrict__ x, const float* __restrict__ Wd,
    const float* __restrict__ bd, const float* __restrict__ emb, float* __restrict__ h, u16* __restrict__ hb)
{
  size_t gid = (size_t)blockIdx.x * 256 + threadIdx.x;  // MENC*512
  int dd = (int)(gid & 511);
  size_t rs = gid >> 9;
  int s = (int)(rs % SPENC);
  int b = (int)(rs / SPENC);
  float v;
  if (s == 0) {
    v = emb[dd];
  } else if (s < SENC) {
    float acc = bd[dd];
    const float* xr = x + ((size_t)b * 1024 + (s - 1)) * 16;
    #pragma unroll
    for (int j = 0; j < 16; ++j) acc += xr[j] * Wd[j * 512 + dd];
    v = acc + emb[(size_t)s * 512 + dd];
  } else {
    v = 0.f;
  }
  h[gid] = v;
  hb[gid] = f2b(v);
}

// ---------- MFMA bf16 GEMM, 128x256 tile, 512 threads (8 waves) ----------
// Triple-buffered LDS + counted vmcnt; output always bf16 (u16) + bias (+ReLU).
// No split-K, no atomics: C[M,N] = A[M,K] @ WT[N,K]^T + bias.
// LDS chunk (16B = 8 bf16): logical k-chunk c of row r stored at slot r*4 + (c ^ ((r>>1)&3)).
template<bool RELU>
__global__ __launch_bounds__(512) void mgemm_k(const u16* __restrict__ A, const u16* __restrict__ WT,
    const float* __restrict__ bias, u16* __restrict__ C,
    int M, int N, int Kc, int lda, int ldb)
{
  __shared__ __align__(16) u16 sA[3][128 * 32];   // 24 KB
  __shared__ __align__(16) u16 sB[3][256 * 32];   // 48 KB
  int t = threadIdx.x;

  // bijective XCD-aware remap of the flattened (x,y) id
  int gx = gridDim.x;
  int nwg = gx * gridDim.y;
  int flat = blockIdx.y * gx + blockIdx.x;
  int q = nwg >> 3, rr = nwg & 7;
  int xcd = flat & 7, idx = flat >> 3;
  int swz = (xcd < rr ? xcd * (q + 1) : rr * (q + 1) + (xcd - rr) * q) + idx;
  int bx = swz % gx, by = swz / gx;

  int n0 = bx * 256, m0 = by * 128;
  int lane = t & 63, wave = t >> 6;            // 8 waves: 2M x 4N
  int wm = (wave >> 2) * 64, wn = (wave & 3) * 64;
  int quad = lane >> 4, l15 = lane & 15;

  // staging: A 1 issue (512 chunks), B 2 issues (1024 chunks); chunk ch -> row ch>>2, slot ch&3
  int rA = t >> 2, sc = t & 3;
  int cA = sc ^ ((rA >> 1) & 3);
  int raA = m0 + rA; raA = raA < M ? raA : M - 1;
  const u16* gA  = A  + (size_t)raA * lda + cA * 8;
  const u16* gB0 = WT + (size_t)(n0 + rA) * ldb + cA * 8;       // rows 0..127
  const u16* gB1 = WT + (size_t)(n0 + 128 + rA) * ldb + cA * 8; // rows 128..255 (same xor)

  f32x4 acc[4][4];
  #pragma unroll
  for (int i = 0; i < 4; ++i)
    #pragma unroll
    for (int j = 0; j < 4; ++j) acc[i][j] = (f32x4){0.f, 0.f, 0.f, 0.f};

  const int nt = Kc >> 5;
  // prologue: stage tile 0 -> buf0, tile 1 -> buf1 (6 loads in flight per wave)
  gload16(gA,      &sA[0][t * 8]);
  gload16(gB0,     &sB[0][t * 8]);
  gload16(gB1,     &sB[0][(512 + t) * 8]);
  gload16(gA + 32, &sA[1][t * 8]);
  gload16(gB0 + 32,&sB[1][t * 8]);
  gload16(gB1 + 32,&sB[1][(512 + t) * 8]);

  int cur = 0;
  for (int tt = 0; tt < nt; ++tt) {
    if (tt < nt - 1) {
      asm volatile("s_waitcnt vmcnt(3)" ::: "memory");   // tile tt landed; tile tt+1 in flight
    } else {
      asm volatile("s_waitcnt vmcnt(0)" ::: "memory");
    }
    __builtin_amdgcn_s_barrier();
    asm volatile("" ::: "memory");
    if (tt + 2 < nt) {
      int k0 = (tt + 2) << 5;
      int nb = tt + 2; nb -= (nb / 3) * 3;               // (tt+2) % 3
      gload16(gA + k0,  &sA[nb][t * 8]);
      gload16(gB0 + k0, &sB[nb][t * 8]);
      gload16(gB1 + k0, &sB[nb][(512 + t) * 8]);
    }
    short8 af[4], bf[4];
    #pragma unroll
    for (int i = 0; i < 4; ++i) {
      int ra = wm + i * 16 + l15;
      af[i] = *(const short8*)&sA[cur][ra * 32 + (quad ^ ((ra >> 1) & 3)) * 8];
    }
    #pragma unroll
    for (int j = 0; j < 4; ++j) {
      int rb = wn + j * 16 + l15;
      bf[j] = *(const short8*)&sB[cur][rb * 32 + (quad ^ ((rb >> 1) & 3)) * 8];
    }
    __builtin_amdgcn_s_setprio(1);
    #pragma unroll
    for (int i = 0; i < 4; ++i)
      #pragma unroll
      for (int j = 0; j < 4; ++j)
        acc[i][j] = __builtin_amdgcn_mfma_f32_16x16x32_bf16(af[i], bf[j], acc[i][j], 0, 0, 0);
    __builtin_amdgcn_s_setprio(0);
    cur = (cur == 2) ? 0 : cur + 1;
  }

  // epilogue: D row = quad*4+reg (m), col = lane&15 (n)  [m89-verified]
  #pragma unroll
  for (int i = 0; i < 4; ++i) {
    int mBase = m0 + wm + i * 16 + quad * 4;
    #pragma unroll
    for (int r = 0; r < 4; ++r) {
      int m = mBase + r;
      if (m < M) {
        #pragma unroll
        for (int j = 0; j < 4; ++j) {
          int n = n0 + wn + j * 16 + l15;
          float v = acc[i][j][r] + bias[n];
          if (RELU) v = fmaxf(v, 0.f);
          C[(size_t)m * N + n] = f2b(v);
        }
      }
    }
  }
}

// ---------- fused residual + LayerNorm: h = LN(h + tmp); emits bf16 shadow ----------
// tmp is the bf16 GEMM output (bias already added). One block per row, shfl reduce.
__global__ __launch_bounds__(256) void lnf_k(float* __restrict__ h, const u16* __restrict__ tmp,
    u16* __restrict__ hb, const float* __restrict__ g, const float* __restrict__ bb)
{
  __shared__ float ls[4], lq[4];
  int t = threadIdx.x;
  float* p = h + (size_t)blockIdx.x * 512;
  const u16* tp = tmp + (size_t)blockIdx.x * 512;
  u16* pb = hb + (size_t)blockIdx.x * 512;
  float2 hv = *(const float2*)&p[2 * t];
  ushort2 tv = *(const ushort2*)&tp[2 * t];
  float v0 = hv.x + b2f(tv.x);
  float v1 = hv.y + b2f(tv.y);
  float s = v0 + v1, qq = v0 * v0 + v1 * v1;
  #pragma unroll
  for (int off = 1; off < 64; off <<= 1) {
    s += __shfl_xor(s, off);
    qq += __shfl_xor(qq, off);
  }
  if ((t & 63) == 0) { ls[t >> 6] = s; lq[t >> 6] = qq; }
  __syncthreads();
  s = ls[0] + ls[1] + ls[2] + ls[3];
  qq = lq[0] + lq[1] + lq[2] + lq[3];
  float mean = s * (1.f / 512.f);
  float var = fmaxf(qq * (1.f / 512.f) - mean * mean, 0.f);
  float rinv = rsqrtf(var + 1e-5f);
  float o0 = (v0 - mean) * rinv * g[2 * t] + bb[2 * t];
  float o1 = (v1 - mean) * rinv * g[2 * t + 1] + bb[2 * t + 1];
  *(float2*)&p[2 * t] = make_float2(o0, o1);
  ushort2 ob; ob.x = f2b(o0); ob.y = f2b(o1);
  *(ushort2*)&pb[2 * t] = ob;
}

// ---------- sparse block attention, MFMA version: one wave per (b, h, n) ----------
__global__ __launch_bounds__(64) void attnm_k(const u16* __restrict__ qkv, u16* __restrict__ av,
    const int* __restrict__ rnd, int S, int Sp, int nb)
{
  __shared__ __align__(16) u16 Vt[64 * 104];
  __shared__ __align__(16) u16 Pl[16 * 104];
  __shared__ int sJB[10], sVD[10];
  int t = threadIdx.x;
  int n = blockIdx.x % nb;
  int r1 = blockIdx.x / nb;
  int hh = r1 & 7, b = r1 >> 3;
  const u16* base = qkv + (size_t)b * Sp * 1536;
  int l15 = t & 15, quad = t >> 4;

  if (t < 10) {
    int jb, vd;
    if (t < 2) { jb = t; vd = 1; }
    else if (t < 7) {
      int w = n + t - 4;
      vd = (w >= 0 && w < nb) ? 1 : 0;
      jb = w < 0 ? 0 : (w > nb - 1 ? nb - 1 : w);
    } else { jb = rnd[n * 3 + t - 7]; vd = 1; }
    sJB[t] = jb; sVD[t] = vd;
  }
  {
    f32x4 zz = {0.f, 0.f, 0.f, 0.f};
    *(f32x4*)&Vt[t * 104 + 80] = zz;
    *(f32x4*)&Vt[t * 104 + 88] = zz;
    if (t < 16) {
      *(f32x4*)&Pl[t * 104 + 80] = zz;
      *(f32x4*)&Pl[t * 104 + 88] = zz;
    }
  }
  __syncthreads();

  short8 aq0, aq1;
  {
    const u16* qp = base + (size_t)(n * 8 + (l15 & 7)) * 1536 + hh * 64 + quad * 8;
    aq0 = *(const short8*)qp;
    aq1 = *(const short8*)(qp + 32);
  }

  f32x4 s[5];
  float okm[5];
  #pragma unroll
  for (int tile = 0; tile < 5; ++tile) {
    int kb = tile * 2 + (l15 >> 3);
    int tok = sJB[kb] * 8 + (l15 & 7);
    okm[tile] = (sVD[kb] && tok < S) ? 0.f : -3.0e38f;
    const u16* kp = base + (size_t)tok * 1536 + 512 + hh * 64 + quad * 8;
    short8 k0 = *(const short8*)kp;
    short8 k1 = *(const short8*)(kp + 32);
    f32x4 c = {0.f, 0.f, 0.f, 0.f};
    c = __builtin_amdgcn_mfma_f32_16x16x32_bf16(aq0, k0, c, 0, 0, 0);
    c = __builtin_amdgcn_mfma_f32_16x16x32_bf16(aq1, k1, c, 0, 0, 0);
    s[tile] = c;
  }

  u16 vreg[80];
  #pragma unroll
  for (int vt = 0; vt < 10; ++vt) {
    const u16* vp = base + (size_t)(sJB[vt] * 8) * 1536 + 1024 + hh * 64 + t;
    #pragma unroll
    for (int j = 0; j < 8; ++j) vreg[vt * 8 + j] = vp[(size_t)j * 1536];
  }

  f32x4 mx = {-3.0e38f, -3.0e38f, -3.0e38f, -3.0e38f};
  #pragma unroll
  for (int tile = 0; tile < 5; ++tile) {
    #pragma unroll
    for (int r = 0; r < 4; ++r) {
      float v = s[tile][r] * 0.125f + okm[tile];
      s[tile][r] = v;
      mx[r] = fmaxf(mx[r], v);
    }
  }
  #pragma unroll
  for (int off = 1; off < 16; off <<= 1) {
    #pragma unroll
    for (int r = 0; r < 4; ++r) mx[r] = fmaxf(mx[r], __shfl_xor(mx[r], off));
  }
  f32x4 sm = {0.f, 0.f, 0.f, 0.f};
  #pragma unroll
  for (int tile = 0; tile < 5; ++tile) {
    #pragma unroll
    for (int r = 0; r < 4; ++r) {
      float e = __expf(s[tile][r] - mx[r]);
      s[tile][r] = e;
      sm[r] += e;
    }
  }
  #pragma unroll
  for (int off = 1; off < 16; off <<= 1) {
    #pragma unroll
    for (int r = 0; r < 4; ++r) sm[r] += __shfl_xor(sm[r], off);
  }

  #pragma unroll
  for (int tile = 0; tile < 5; ++tile)
    #pragma unroll
    for (int r = 0; r < 4; ++r)
      Pl[(quad * 4 + r) * 104 + tile * 16 + l15] = f2b(s[tile][r]);

  #pragma unroll
  for (int vt = 0; vt < 10; ++vt) {
    short8 w;
    #pragma unroll
    for (int j = 0; j < 8; ++j) ((u16*)&w)[j] = (short)vreg[vt * 8 + j];
    *(short8*)&Vt[t * 104 + vt * 8] = w;
  }
  __syncthreads();

  f32x4 o[4];
  #pragma unroll
  for (int dn = 0; dn < 4; ++dn) o[dn] = (f32x4){0.f, 0.f, 0.f, 0.f};
  #pragma unroll
  for (int ks = 0; ks < 3; ++ks) {
    short8 ap = *(const short8*)&Pl[l15 * 104 + ks * 32 + quad * 8];
    #pragma unroll
    for (int dn = 0; dn < 4; ++dn) {
      short8 bv = *(const short8*)&Vt[(dn * 16 + l15) * 104 + ks * 32 + quad * 8];
      o[dn] = __builtin_amdgcn_mfma_f32_16x16x32_bf16(ap, bv, o[dn], 0, 0, 0);
    }
  }

  if (quad < 2) {
    #pragma unroll
    for (int r = 0; r < 4; ++r) {
      int qi = quad * 4 + r;
      float inv = 1.f / sm[r];
      u16* op = av + ((size_t)b * Sp + n * 8 + qi) * 512 + hh * 64 + l15;
      #pragma unroll
      for (int dn = 0; dn < 4; ++dn)
        op[dn * 16] = f2b(o[dn][r] * inv);
    }
  }
}

// ---------- VAE head ----------
__global__ __launch_bounds__(512) void head_k(const float* __restrict__ h,
    const float* __restrict__ Wm, const float* __restrict__ bm,
    const float* __restrict__ Wlv, const float* __restrict__ blv,
    const float* __restrict__ eps, float* __restrict__ z, float* out_elbo)
{
  __shared__ float red[512];
  int t = threadIdx.x;
  int b = t >> 4, i = t & 15;
  const float* p = h + (size_t)b * SPENC * 512;
  float am = bm[i], al = blv[i];
  for (int c = 0; c < 512; ++c) {
    float pv = p[c];
    am += pv * Wm[c * 16 + i];
    al += pv * Wlv[c * 16 + i];
  }
  z[t] = am + eps[t] * expf(0.5f * al);
  red[t] = -0.5f * (1.f + al - am * am - expf(al));
  __syncthreads();
  for (int o = 256; o > 0; o >>= 1) { if (t < o) red[t] += red[t + o]; __syncthreads(); }
  if (t == 0) out_elbo[0] = red[0] * (1.f / 32.f);
}

// ---------- seq ----------
__global__ __launch_bounds__(256) void seq_k(const float* __restrict__ z, const float* __restrict__ We,
    const float* __restrict__ be, float* __restrict__ seq)
{
  int gid = blockIdx.x * 256 + threadIdx.x;
  int b = gid >> 11, c = gid & 2047;
  float acc = be[c];
  #pragma unroll
  for (int i = 0; i < 16; ++i) acc += z[b * 16 + i] * We[i * 2048 + c];
  seq[gid] = acc;
}

// ---------- decoder init: h fp32 + hb bf16 ----------
__global__ __launch_bounds__(256) void decinit_k(const float* __restrict__ seq, const float* __restrict__ Wc,
    const float* __restrict__ bc, const float* __restrict__ emb, float* __restrict__ h, u16* __restrict__ hb)
{
  size_t gid = (size_t)blockIdx.x * 256 + threadIdx.x;
  int dd = (int)(gid & 511);
  size_t rs = gid >> 9;
  int s = (int)(rs & 1023);
  int b = (int)(rs >> 10);
  float v = seq[b * 2048 + s] * Wc[dd] + seq[b * 2048 + 1024 + s] * Wc[512 + dd]
          + bc[dd] + emb[(size_t)s * 512 + dd];
  h[gid] = v;
  hb[gid] = f2b(v);
}

// ---------- final: out[M,16] = hb[M,512] @ Wseq[512,16] + bs, via MFMA ----------
// Block = 256 thr (4 waves); wave w covers rows m0+w*16..+15; K-loop 16 x mfma_16x16x32.
// Wseq staged once per block into LDS bf16 [16][520] (520-stride: 2-way bank max).
__global__ __launch_bounds__(256) void finalm_k(const u16* __restrict__ hb, const float* __restrict__ Ws,
    const float* __restrict__ bs, float* __restrict__ out)
{
  __shared__ __align__(16) u16 Wt[16 * 520];
  int t = threadIdx.x;
  for (int e = t; e < 8192; e += 256) {
    int k = e >> 4, n = e & 15;
    Wt[n * 520 + k] = f2b(Ws[e]);
  }
  __syncthreads();
  int lane = t & 63, wave = t >> 6;
  int quad = lane >> 4, l15 = lane & 15;
  int m0 = blockIdx.x * 64 + wave * 16;
  const u16* arow = hb + (size_t)(m0 + l15) * 512 + quad * 8;
  f32x4 acc = (f32x4){0.f, 0.f, 0.f, 0.f};
  #pragma unroll
  for (int ks = 0; ks < 16; ++ks) {
    short8 af = *(const short8*)(arow + ks * 32);
    short8 bf = *(const short8*)&Wt[l15 * 520 + ks * 32 + quad * 8];
    acc = __builtin_amdgcn_mfma_f32_16x16x32_bf16(af, bf, acc, 0, 0, 0);
  }
  // C layout: row = quad*4+r, col = l15
  #pragma unroll
  for (int r = 0; r < 4; ++r)
    out[(size_t)(m0 + quad * 4 + r) * 16 + l15] = acc[r] + bs[l15];
}

extern "C" void kernel_launch(void* const* d_in, const int* in_sizes, int n_in,
                              void* d_out, int out_size, void* d_ws, size_t ws_size,
                              hipStream_t stream) {
  float* out = (float*)d_out;
  (void)out_size; (void)ws_size;

  static const int EXP_DICT[30] = {
    524288, 512, 524800, 524288, 8192, 512, 7864320, 15360, 2621440, 5120,
    5120, 5120, 10485760, 20480, 10485760, 5120, 5120, 5120, 8192, 16,
    8192, 16, 32768, 2048, 1024, 512, 8192, 16, 387, 384 };
  bool dict_ok = (n_in == 30);
  if (dict_ok) for (int i = 0; i < 30; ++i) if (in_sizes[i] != EXP_DICT[i]) { dict_ok = false; break; }
  if (!dict_ok) { beacon_k<<<1, 64, 0, stream>>>(out); return; }

  const float* x      = (const float*)d_in[0];
  const float* eps    = (const float*)d_in[1];
  const float* emb_in = (const float*)d_in[2];
  const float* emb_out= (const float*)d_in[3];
  const float* W_data = (const float*)d_in[4];
  const float* b_data = (const float*)d_in[5];
  const float* Wqkv   = (const float*)d_in[6];
  const float* bqkv   = (const float*)d_in[7];
  const float* Wo     = (const float*)d_in[8];
  const float* bo     = (const float*)d_in[9];
  const float* ln1g   = (const float*)d_in[10];
  const float* ln1b   = (const float*)d_in[11];
  const float* W1     = (const float*)d_in[12];
  const float* b1     = (const float*)d_in[13];
  const float* W2     = (const float*)d_in[14];
  const float* b2     = (const float*)d_in[15];
  const float* ln2g   = (const float*)d_in[16];
  const float* ln2b   = (const float*)d_in[17];
  const float* Wm     = (const float*)d_in[18];
  const float* bm     = (const float*)d_in[19];
  const float* Wlv    = (const float*)d_in[20];
  const float* blv    = (const float*)d_in[21];
  const float* Wexp   = (const float*)d_in[22];
  const float* bexp   = (const float*)d_in[23];
  const float* Wconv  = (const float*)d_in[24];
  const float* bconv  = (const float*)d_in[25];
  const float* Wseq   = (const float*)d_in[26];
  const float* bseq   = (const float*)d_in[27];
  const int* rand_enc = (const int*)d_in[28];
  const int* rand_dec = (const int*)d_in[29];

  // ---- workspace carve (~194.5 MB; proven-safe envelope 203 MB) ----
  // union region U = [126615552, 194248704):
  //   attn phase: qkvb (50.7 MB) + avb (16.9 MB)
  //   Wo phase:   tmpo = U (<=33.8 MB; qkvb dead after attn)
  //   FFN phase:  ffnb = U (<=45.1 MB, Mc<=11008) + tmpF = U+45088768 (<=11.3 MB)
  char* ws = (char*)d_ws;
  float* h     = (float*)ws;
  u16*   hb    = (u16*)(ws + 67633152);
  u16*   WTqkv = (u16*)(ws + 101449728);
  u16*   WTo   = (u16*)(ws + 117178368);
  u16*   WT1l  = (u16*)(ws + 122421248);
  u16*   WT2l  = (u16*)(ws + 124518400);
  u16*   qkvb  = (u16*)(ws + 126615552);
  u16*   avb   = (u16*)(ws + 126615552 + 50724864);
  u16*   tmpo  = (u16*)(ws + 126615552);             // Wo-phase temp (union reuse)
  u16*   ffnb  = (u16*)(ws + 126615552);             // FFN activations (union reuse)
  u16*   tmpF  = (u16*)(ws + 126615552 + 45088768);  // W2 temp (after ffnb)
  float* seqb  = (float*)(ws + 194248704);
  float* z     = (float*)(ws + 194510848);

  // ---- persistent weight transpose+convert (qkv, o for all 10 layers) ----
  tr_k<<<dim3(512 / 32, 1536 / 32, 10), 256, 0, stream>>>(Wqkv, WTqkv, 512, 1536);
  tr_k<<<dim3(512 / 32, 512 / 32, 10), 256, 0, stream>>>(Wo, WTo, 512, 512);

  // ===== encoder: M=33024 =====
  {
    const int M = MENC;
    embed_k<<<(M * 512) / 256, 256, 0, stream>>>(x, W_data, b_data, emb_in, h, hb);
    for (int i = 0; i < 5; ++i) {
      // attention path: 2 chunks of 16 batches (Mc=16512)
      for (int bc = 0; bc < 2; ++bc) {
        size_t roff = (size_t)bc * 16 * SPENC * 512;
        const int Mc = 16 * SPENC;  // 16512
        const int ty = 129;         // 16512/128
        mgemm_k<false><<<dim3(6, ty), 512, 0, stream>>>(
            hb + roff, WTqkv + (size_t)i * 512 * 1536, bqkv + (size_t)i * 1536, qkvb, Mc, 1536, 512, 512, 512);
        attnm_k<<<16 * 8 * NBE, 64, 0, stream>>>(qkvb, avb, rand_enc, SENC, SPENC, NBE);
        mgemm_k<false><<<dim3(2, ty), 512, 0, stream>>>(
            avb, WTo + (size_t)i * 512 * 512, bo + (size_t)i * 512, tmpo, Mc, 512, 512, 512, 512);
        lnf_k<<<Mc, 256, 0, stream>>>(h + roff, tmpo, hb + roff, ln1g + (size_t)i * 512, ln1b + (size_t)i * 512);
      }
      // per-layer FFN weight transposes
      tr_k<<<dim3(512 / 32, 2048 / 32, 1), 256, 0, stream>>>(W1 + (size_t)i * 512 * 2048, WT1l, 512, 2048);
      tr_k<<<dim3(2048 / 32, 512 / 32, 1), 256, 0, stream>>>(W2 + (size_t)i * 2048 * 512, WT2l, 2048, 512);
      // FFN: 3 chunks of 11008 rows (33024 = 3*11008)
      for (int cc = 0; cc < 3; ++cc) {
        size_t off = (size_t)cc * 11008;
        const int Mc = 11008;
        const int ty = 86;  // 11008/128
        mgemm_k<true><<<dim3(8, ty), 512, 0, stream>>>(
            hb + off * 512, WT1l, b1 + (size_t)i * 2048, ffnb, Mc, 2048, 512, 512, 512);
        mgemm_k<false><<<dim3(2, ty), 512, 0, stream>>>(
            ffnb, WT2l, b2 + (size_t)i * 512, tmpF, Mc, 512, 2048, 2048, 2048);
        lnf_k<<<Mc, 256, 0, stream>>>(h + off * 512, tmpF, hb + off * 512, ln2g + (size_t)i * 512, ln2b + (size_t)i * 512);
      }
    }
  }

  // ===== VAE head =====
  head_k<<<1, 512, 0, stream>>>(h, Wm, bm, Wlv, blv, eps, z, out + 524288);
  seq_k<<<256, 256, 0, stream>>>(z, Wexp, bexp, seqb);
  decinit_k<<<(MDEC * 512) / 256, 256, 0, stream>>>(seqb, Wconv, bconv, emb_out, h, hb);

  // ===== decoder: M=32768 =====
  {
    for (int i = 5; i < 10; ++i) {
      for (int bc = 0; bc < 2; ++bc) {
        size_t roff = (size_t)bc * 16 * SDEC * 512;
        const int Mc = 16 * SDEC;  // 16384
        const int ty = 128;
        mgemm_k<false><<<dim3(6, ty), 512, 0, stream>>>(
            hb + roff, WTqkv + (size_t)i * 512 * 1536, bqkv + (size_t)i * 1536, qkvb, Mc, 1536, 512, 512, 512);
        attnm_k<<<16 * 8 * NBD, 64, 0, stream>>>(qkvb, avb, rand_dec, SDEC, SDEC, NBD);
        mgemm_k<false><<<dim3(2, ty), 512, 0, stream>>>(
            avb, WTo + (size_t)i * 512 * 512, bo + (size_t)i * 512, tmpo, Mc, 512, 512, 512, 512);
        lnf_k<<<Mc, 256, 0, stream>>>(h + roff, tmpo, hb + roff, ln1g + (size_t)i * 512, ln1b + (size_t)i * 512);
      }
      tr_k<<<dim3(512 / 32, 2048 / 32, 1), 256, 0, stream>>>(W1 + (size_t)i * 512 * 2048, WT1l, 512, 2048);
      tr_k<<<dim3(2048 / 32, 512 / 32, 1), 256, 0, stream>>>(W2 + (size_t)i * 2048 * 512, WT2l, 2048, 512);
      // FFN: chunks 11008, 11008, 10752 (32768 total)
      static const int DOFF[3] = {0, 11008, 22016};
      static const int DMC[3]  = {11008, 11008, 10752};
      for (int cc = 0; cc < 3; ++cc) {
        size_t off = (size_t)DOFF[cc];
        const int Mc = DMC[cc];
        const int ty = Mc / 128;  // 86, 86, 84
        mgemm_k<true><<<dim3(8, ty), 512, 0, stream>>>(
            hb + off * 512, WT1l, b1 + (size_t)i * 2048, ffnb, Mc, 2048, 512, 512, 512);
        mgemm_k<false><<<dim3(2, ty), 512, 0, stream>>>(
            ffnb, WT2l, b2 + (size_t)i * 512, tmpF, Mc, 512, 2048, 2048, 2048);
        lnf_k<<<Mc, 256, 0, stream>>>(h + off * 512, tmpF, hb + off * 512, ln2g + (size_t)i * 512, ln2b + (size_t)i * 512);
      }
    }
  }

  // ===== output =====
  finalm_k<<<MDEC / 64, 256, 0, stream>>>(hb, Wseq, bseq, out);
}

// Round 11
// 5843.446 us; speedup vs baseline: 1.2384x; 1.0425x over previous
//
#include <hip/hip_runtime.h>

typedef unsigned short u16;
typedef __attribute__((ext_vector_type(8))) short short8;
typedef __attribute__((ext_vector_type(4))) float f32x4;

__device__ __forceinline__ float b2f(u16 h) {
  union { unsigned int u; float f; } v; v.u = ((unsigned int)h) << 16; return v.f;
}
__device__ __forceinline__ u16 f2b(float f) {
  union { float f; unsigned int u; } v; v.f = f;
  return (u16)((v.u + 0x7fffu + ((v.u >> 16) & 1u)) >> 16);
}

// async global->LDS, 16B per lane; dst must be wave-base + lane*16 (m97 pattern)
__device__ __forceinline__ void gload16(const u16* g, u16* l) {
  __builtin_amdgcn_global_load_lds(
      (const __attribute__((address_space(1))) void*)g,
      (__attribute__((address_space(3))) void*)l, 16, 0, 0);
}

#define SENC 1025
#define SPENC 1032
#define NBE 129
#define SDEC 1024
#define NBD 128
#define BATCH 32
#define MENC (BATCH * SPENC)  /* 33024 */
#define MDEC (BATCH * SDEC)   /* 32768 */

// ---------- beacon ----------
__global__ void beacon_k(float* out) { if (threadIdx.x == 0) out[0] = 1000.0f; }

// ---------- weight transpose + bf16 convert: WT[n][k] = bf16(W[k][n]) ----------
__global__ __launch_bounds__(256) void tr_k(const float* __restrict__ W, u16* __restrict__ WT, int K, int N)
{
  __shared__ float sm[32][33];
  int k0 = blockIdx.x * 32, n0 = blockIdx.y * 32;
  const float* Wz = W + (size_t)blockIdx.z * K * N;
  u16* WTz = WT + (size_t)blockIdx.z * K * N;
  int r = threadIdx.x >> 3, c0 = (threadIdx.x & 7) * 4;
  float4 v = *(const float4*)&Wz[(size_t)(k0 + r) * N + n0 + c0];
  sm[r][c0] = v.x; sm[r][c0 + 1] = v.y; sm[r][c0 + 2] = v.z; sm[r][c0 + 3] = v.w;
  __syncthreads();
  ushort4 u;
  u.x = f2b(sm[c0][r]); u.y = f2b(sm[c0 + 1][r]); u.z = f2b(sm[c0 + 2][r]); u.w = f2b(sm[c0 + 3][r]);
  *(ushort4*)&WTz[(size_t)(n0 + r) * K + k0 + c0] = u;
}

// ---------- embed: h fp32 + hb bf16 ----------
__global__ __launch_bounds__(256) void embed_k(const float* __restrict__ x, const float* __restrict__ Wd,
    const float* __restrict__ bd, const float* __restrict__ emb, float* __restrict__ h, u16* __restrict__ hb)
{
  size_t gid = (size_t)blockIdx.x * 256 + threadIdx.x;  // MENC*512
  int dd = (int)(gid & 511);
  size_t rs = gid >> 9;
  int s = (int)(rs % SPENC);
  int b = (int)(rs / SPENC);
  float v;
  if (s == 0) {
    v = emb[dd];
  } else if (s < SENC) {
    float acc = bd[dd];
    const float* xr = x + ((size_t)b * 1024 + (s - 1)) * 16;
    #pragma unroll
    for (int j = 0; j < 16; ++j) acc += xr[j] * Wd[j * 512 + dd];
    v = acc + emb[(size_t)s * 512 + dd];
  } else {
    v = 0.f;
  }
  h[gid] = v;
  hb[gid] = f2b(v);
}

// ---------- MFMA bf16 GEMM, 128x256 tile, 512 threads (8 waves) ----------
// Triple-buffered LDS + counted vmcnt; output bf16 + bias (+ReLU).
// LDS chunk (16B = 8 bf16): logical k-chunk c of row r stored at slot r*4 + (c ^ ((r>>1)&3)).
template<bool RELU>
__global__ __launch_bounds__(512) void mgemm_k(const u16* __restrict__ A, const u16* __restrict__ WT,
    const float* __restrict__ bias, u16* __restrict__ C,
    int M, int N, int Kc, int lda, int ldb)
{
  __shared__ __align__(16) u16 sA[3][128 * 32];   // 24 KB
  __shared__ __align__(16) u16 sB[3][256 * 32];   // 48 KB
  int t = threadIdx.x;

  // bijective XCD-aware remap of the flattened (x,y) id
  int gx = gridDim.x;
  int nwg = gx * gridDim.y;
  int flat = blockIdx.y * gx + blockIdx.x;
  int q = nwg >> 3, rr = nwg & 7;
  int xcd = flat & 7, idx = flat >> 3;
  int swz = (xcd < rr ? xcd * (q + 1) : rr * (q + 1) + (xcd - rr) * q) + idx;
  int bx = swz % gx, by = swz / gx;

  int n0 = bx * 256, m0 = by * 128;
  int lane = t & 63, wave = t >> 6;            // 8 waves: 2M x 4N
  int wm = (wave >> 2) * 64, wn = (wave & 3) * 64;
  int quad = lane >> 4, l15 = lane & 15;

  int rA = t >> 2, sc = t & 3;
  int cA = sc ^ ((rA >> 1) & 3);
  int raA = m0 + rA; raA = raA < M ? raA : M - 1;
  const u16* gA  = A  + (size_t)raA * lda + cA * 8;
  const u16* gB0 = WT + (size_t)(n0 + rA) * ldb + cA * 8;       // rows 0..127
  const u16* gB1 = WT + (size_t)(n0 + 128 + rA) * ldb + cA * 8; // rows 128..255 (same xor)

  f32x4 acc[4][4];
  #pragma unroll
  for (int i = 0; i < 4; ++i)
    #pragma unroll
    for (int j = 0; j < 4; ++j) acc[i][j] = (f32x4){0.f, 0.f, 0.f, 0.f};

  const int nt = Kc >> 5;
  gload16(gA,      &sA[0][t * 8]);
  gload16(gB0,     &sB[0][t * 8]);
  gload16(gB1,     &sB[0][(512 + t) * 8]);
  gload16(gA + 32, &sA[1][t * 8]);
  gload16(gB0 + 32,&sB[1][t * 8]);
  gload16(gB1 + 32,&sB[1][(512 + t) * 8]);

  int cur = 0;
  for (int tt = 0; tt < nt; ++tt) {
    if (tt < nt - 1) {
      asm volatile("s_waitcnt vmcnt(3)" ::: "memory");
    } else {
      asm volatile("s_waitcnt vmcnt(0)" ::: "memory");
    }
    __builtin_amdgcn_s_barrier();
    asm volatile("" ::: "memory");
    if (tt + 2 < nt) {
      int k0 = (tt + 2) << 5;
      int nb = tt + 2; nb -= (nb / 3) * 3;               // (tt+2) % 3
      gload16(gA + k0,  &sA[nb][t * 8]);
      gload16(gB0 + k0, &sB[nb][t * 8]);
      gload16(gB1 + k0, &sB[nb][(512 + t) * 8]);
    }
    short8 af[4], bf[4];
    #pragma unroll
    for (int i = 0; i < 4; ++i) {
      int ra = wm + i * 16 + l15;
      af[i] = *(const short8*)&sA[cur][ra * 32 + (quad ^ ((ra >> 1) & 3)) * 8];
    }
    #pragma unroll
    for (int j = 0; j < 4; ++j) {
      int rb = wn + j * 16 + l15;
      bf[j] = *(const short8*)&sB[cur][rb * 32 + (quad ^ ((rb >> 1) & 3)) * 8];
    }
    __builtin_amdgcn_s_setprio(1);
    #pragma unroll
    for (int i = 0; i < 4; ++i)
      #pragma unroll
      for (int j = 0; j < 4; ++j)
        acc[i][j] = __builtin_amdgcn_mfma_f32_16x16x32_bf16(af[i], bf[j], acc[i][j], 0, 0, 0);
    __builtin_amdgcn_s_setprio(0);
    cur = (cur == 2) ? 0 : cur + 1;
  }

  #pragma unroll
  for (int i = 0; i < 4; ++i) {
    int mBase = m0 + wm + i * 16 + quad * 4;
    #pragma unroll
    for (int r = 0; r < 4; ++r) {
      int m = mBase + r;
      if (m < M) {
        #pragma unroll
        for (int j = 0; j < 4; ++j) {
          int n = n0 + wn + j * 16 + l15;
          float v = acc[i][j][r] + bias[n];
          if (RELU) v = fmaxf(v, 0.f);
          C[(size_t)m * N + n] = f2b(v);
        }
      }
    }
  }
}

// ---------- fused GEMM(N=512) + residual + LayerNorm ----------
// One block owns 128 rows x ALL 512 cols. Tile 128M x 512N, 8 waves (2M x 4N),
// per-wave 64x128 (acc[4][8]). Double-buffered LDS (R1-proven loop).
// Epilogue: v = acc + bias + h[row][col] (f32); row mean/var via quad-shfl +
// 4-wide LDS cross-wave reduce; writes h (fp32) and hb (bf16). lnf_k eliminated.
// Requires M % 128 == 0 (all call sites satisfy).
__global__ __launch_bounds__(512) void mgemmln_k(const u16* __restrict__ A, const u16* __restrict__ WT,
    const float* __restrict__ bias, float* __restrict__ h, u16* __restrict__ hb,
    const float* __restrict__ g, const float* __restrict__ bbv_,
    int M, int Kc, int lda)
{
  __shared__ __align__(16) u16 sA[2][128 * 32];   // 16 KB
  __shared__ __align__(16) u16 sB[2][512 * 32];   // 64 KB
  __shared__ float redS[128][4], redQ[128][4];    // 4 KB
  int t = threadIdx.x;
  int m0 = blockIdx.x * 128;
  int lane = t & 63, wave = t >> 6;               // 8 waves: 2M x 4N
  int wm = (wave >> 2) * 64, wn = (wave & 3) * 128;
  int quad = lane >> 4, l15 = lane & 15;
  int wnid = wave & 3;

  // staging: A 1 issue (rows 0..127), B 4 issues (rows 0..511); same xor slotting
  int rA = t >> 2, sc = t & 3;
  int cA = sc ^ ((rA >> 1) & 3);
  const u16* gA = A + (size_t)(m0 + rA) * lda + cA * 8;
  const u16* gB = WT + (size_t)rA * Kc + cA * 8;  // +128*Kc per extra issue (xor invariant)

  f32x4 acc[4][8];
  #pragma unroll
  for (int i = 0; i < 4; ++i)
    #pragma unroll
    for (int j = 0; j < 8; ++j) acc[i][j] = (f32x4){0.f, 0.f, 0.f, 0.f};

  const int nt = Kc >> 5;
  // prologue: stage tile 0 into buf 0
  gload16(gA, &sA[0][t * 8]);
  #pragma unroll
  for (int b4 = 0; b4 < 4; ++b4)
    gload16(gB + (size_t)b4 * 128 * Kc, &sB[0][(b4 * 512 + t) * 8]);
  int cur = 0;
  for (int tt = 0; tt < nt; ++tt) {
    __syncthreads();  // drains vmcnt(0): buf[cur] ready; prior reads of buf[cur^1] done
    if (tt + 1 < nt) {
      int k0 = (tt + 1) << 5;
      gload16(gA + k0, &sA[cur ^ 1][t * 8]);
      #pragma unroll
      for (int b4 = 0; b4 < 4; ++b4)
        gload16(gB + (size_t)b4 * 128 * Kc + k0, &sB[cur ^ 1][(b4 * 512 + t) * 8]);
    }
    short8 af[4], bf[8];
    #pragma unroll
    for (int i = 0; i < 4; ++i) {
      int ra = wm + i * 16 + l15;
      af[i] = *(const short8*)&sA[cur][ra * 32 + (quad ^ ((ra >> 1) & 3)) * 8];
    }
    #pragma unroll
    for (int j = 0; j < 8; ++j) {
      int rb = wn + j * 16 + l15;
      bf[j] = *(const short8*)&sB[cur][rb * 32 + (quad ^ ((rb >> 1) & 3)) * 8];
    }
    __builtin_amdgcn_s_setprio(1);
    #pragma unroll
    for (int i = 0; i < 4; ++i)
      #pragma unroll
      for (int j = 0; j < 8; ++j)
        acc[i][j] = __builtin_amdgcn_mfma_f32_16x16x32_bf16(af[i], bf[j], acc[i][j], 0, 0, 0);
    __builtin_amdgcn_s_setprio(0);
    cur ^= 1;
  }

  // ---------- epilogue: residual add + row stats ----------
  float bsv[8];
  #pragma unroll
  for (int j = 0; j < 8; ++j) bsv[j] = bias[wn + j * 16 + l15];

  #pragma unroll
  for (int i = 0; i < 4; ++i) {
    #pragma unroll
    for (int r = 0; r < 4; ++r) {
      int lr = wm + i * 16 + quad * 4 + r;
      const float* hrow = h + (size_t)(m0 + lr) * 512 + wn + l15;
      float s = 0.f, qq = 0.f;
      #pragma unroll
      for (int j = 0; j < 8; ++j) {
        float v = acc[i][j][r] + bsv[j] + hrow[j * 16];
        acc[i][j][r] = v;
        s += v; qq += v * v;
      }
      #pragma unroll
      for (int off = 1; off < 16; off <<= 1) {
        s += __shfl_xor(s, off);
        qq += __shfl_xor(qq, off);
      }
      if (l15 == 0) { redS[lr][wnid] = s; redQ[lr][wnid] = qq; }
    }
  }
  __syncthreads();
  float gv[8], bv[8];
  #pragma unroll
  for (int j = 0; j < 8; ++j) {
    gv[j] = g[wn + j * 16 + l15];
    bv[j] = bbv_[wn + j * 16 + l15];
  }
  #pragma unroll
  for (int i = 0; i < 4; ++i) {
    #pragma unroll
    for (int r = 0; r < 4; ++r) {
      int lr = wm + i * 16 + quad * 4 + r;
      float s = redS[lr][0] + redS[lr][1] + redS[lr][2] + redS[lr][3];
      float qq = redQ[lr][0] + redQ[lr][1] + redQ[lr][2] + redQ[lr][3];
      float mean = s * (1.f / 512.f);
      float var = fmaxf(qq * (1.f / 512.f) - mean * mean, 0.f);
      float rinv = rsqrtf(var + 1e-5f);
      float* hrow = h + (size_t)(m0 + lr) * 512 + wn + l15;
      u16* hbrow = hb + (size_t)(m0 + lr) * 512 + wn + l15;
      #pragma unroll
      for (int j = 0; j < 8; ++j) {
        float o = (acc[i][j][r] - mean) * rinv * gv[j] + bv[j];
        hrow[j * 16] = o;
        hbrow[j * 16] = f2b(o);
      }
    }
  }
}

// ---------- sparse block attention, MFMA version: one wave per (b, h, n) ----------
__global__ __launch_bounds__(64) void attnm_k(const u16* __restrict__ qkv, u16* __restrict__ av,
    const int* __restrict__ rnd, int S, int Sp, int nb)
{
  __shared__ __align__(16) u16 Vt[64 * 104];
  __shared__ __align__(16) u16 Pl[16 * 104];
  __shared__ int sJB[10], sVD[10];
  int t = threadIdx.x;
  int n = blockIdx.x % nb;
  int r1 = blockIdx.x / nb;
  int hh = r1 & 7, b = r1 >> 3;
  const u16* base = qkv + (size_t)b * Sp * 1536;
  int l15 = t & 15, quad = t >> 4;

  if (t < 10) {
    int jb, vd;
    if (t < 2) { jb = t; vd = 1; }
    else if (t < 7) {
      int w = n + t - 4;
      vd = (w >= 0 && w < nb) ? 1 : 0;
      jb = w < 0 ? 0 : (w > nb - 1 ? nb - 1 : w);
    } else { jb = rnd[n * 3 + t - 7]; vd = 1; }
    sJB[t] = jb; sVD[t] = vd;
  }
  {
    f32x4 zz = {0.f, 0.f, 0.f, 0.f};
    *(f32x4*)&Vt[t * 104 + 80] = zz;
    *(f32x4*)&Vt[t * 104 + 88] = zz;
    if (t < 16) {
      *(f32x4*)&Pl[t * 104 + 80] = zz;
      *(f32x4*)&Pl[t * 104 + 88] = zz;
    }
  }
  __syncthreads();

  short8 aq0, aq1;
  {
    const u16* qp = base + (size_t)(n * 8 + (l15 & 7)) * 1536 + hh * 64 + quad * 8;
    aq0 = *(const short8*)qp;
    aq1 = *(const short8*)(qp + 32);
  }

  f32x4 s[5];
  float okm[5];
  #pragma unroll
  for (int tile = 0; tile < 5; ++tile) {
    int kb = tile * 2 + (l15 >> 3);
    int tok = sJB[kb] * 8 + (l15 & 7);
    okm[tile] = (sVD[kb] && tok < S) ? 0.f : -3.0e38f;
    const u16* kp = base + (size_t)tok * 1536 + 512 + hh * 64 + quad * 8;
    short8 k0 = *(const short8*)kp;
    short8 k1 = *(const short8*)(kp + 32);
    f32x4 c = {0.f, 0.f, 0.f, 0.f};
    c = __builtin_amdgcn_mfma_f32_16x16x32_bf16(aq0, k0, c, 0, 0, 0);
    c = __builtin_amdgcn_mfma_f32_16x16x32_bf16(aq1, k1, c, 0, 0, 0);
    s[tile] = c;
  }

  u16 vreg[80];
  #pragma unroll
  for (int vt = 0; vt < 10; ++vt) {
    const u16* vp = base + (size_t)(sJB[vt] * 8) * 1536 + 1024 + hh * 64 + t;
    #pragma unroll
    for (int j = 0; j < 8; ++j) vreg[vt * 8 + j] = vp[(size_t)j * 1536];
  }

  f32x4 mx = {-3.0e38f, -3.0e38f, -3.0e38f, -3.0e38f};
  #pragma unroll
  for (int tile = 0; tile < 5; ++tile) {
    #pragma unroll
    for (int r = 0; r < 4; ++r) {
      float v = s[tile][r] * 0.125f + okm[tile];
      s[tile][r] = v;
      mx[r] = fmaxf(mx[r], v);
    }
  }
  #pragma unroll
  for (int off = 1; off < 16; off <<= 1) {
    #pragma unroll
    for (int r = 0; r < 4; ++r) mx[r] = fmaxf(mx[r], __shfl_xor(mx[r], off));
  }
  f32x4 sm = {0.f, 0.f, 0.f, 0.f};
  #pragma unroll
  for (int tile = 0; tile < 5; ++tile) {
    #pragma unroll
    for (int r = 0; r < 4; ++r) {
      float e = __expf(s[tile][r] - mx[r]);
      s[tile][r] = e;
      sm[r] += e;
    }
  }
  #pragma unroll
  for (int off = 1; off < 16; off <<= 1) {
    #pragma unroll
    for (int r = 0; r < 4; ++r) sm[r] += __shfl_xor(sm[r], off);
  }

  #pragma unroll
  for (int tile = 0; tile < 5; ++tile)
    #pragma unroll
    for (int r = 0; r < 4; ++r)
      Pl[(quad * 4 + r) * 104 + tile * 16 + l15] = f2b(s[tile][r]);

  #pragma unroll
  for (int vt = 0; vt < 10; ++vt) {
    short8 w;
    #pragma unroll
    for (int j = 0; j < 8; ++j) ((u16*)&w)[j] = (short)vreg[vt * 8 + j];
    *(short8*)&Vt[t * 104 + vt * 8] = w;
  }
  __syncthreads();

  f32x4 o[4];
  #pragma unroll
  for (int dn = 0; dn < 4; ++dn) o[dn] = (f32x4){0.f, 0.f, 0.f, 0.f};
  #pragma unroll
  for (int ks = 0; ks < 3; ++ks) {
    short8 ap = *(const short8*)&Pl[l15 * 104 + ks * 32 + quad * 8];
    #pragma unroll
    for (int dn = 0; dn < 4; ++dn) {
      short8 bv = *(const short8*)&Vt[(dn * 16 + l15) * 104 + ks * 32 + quad * 8];
      o[dn] = __builtin_amdgcn_mfma_f32_16x16x32_bf16(ap, bv, o[dn], 0, 0, 0);
    }
  }

  if (quad < 2) {
    #pragma unroll
    for (int r = 0; r < 4; ++r) {
      int qi = quad * 4 + r;
      float inv = 1.f / sm[r];
      u16* op = av + ((size_t)b * Sp + n * 8 + qi) * 512 + hh * 64 + l15;
      #pragma unroll
      for (int dn = 0; dn < 4; ++dn)
        op[dn * 16] = f2b(o[dn][r] * inv);
    }
  }
}

// ---------- VAE head ----------
__global__ __launch_bounds__(512) void head_k(const float* __restrict__ h,
    const float* __restrict__ Wm, const float* __restrict__ bm,
    const float* __restrict__ Wlv, const float* __restrict__ blv,
    const float* __restrict__ eps, float* __restrict__ z, float* out_elbo)
{
  __shared__ float red[512];
  int t = threadIdx.x;
  int b = t >> 4, i = t & 15;
  const float* p = h + (size_t)b * SPENC * 512;
  float am = bm[i], al = blv[i];
  for (int c = 0; c < 512; ++c) {
    float pv = p[c];
    am += pv * Wm[c * 16 + i];
    al += pv * Wlv[c * 16 + i];
  }
  z[t] = am + eps[t] * expf(0.5f * al);
  red[t] = -0.5f * (1.f + al - am * am - expf(al));
  __syncthreads();
  for (int o = 256; o > 0; o >>= 1) { if (t < o) red[t] += red[t + o]; __syncthreads(); }
  if (t == 0) out_elbo[0] = red[0] * (1.f / 32.f);
}

// ---------- seq ----------
__global__ __launch_bounds__(256) void seq_k(const float* __restrict__ z, const float* __restrict__ We,
    const float* __restrict__ be, float* __restrict__ seq)
{
  int gid = blockIdx.x * 256 + threadIdx.x;
  int b = gid >> 11, c = gid & 2047;
  float acc = be[c];
  #pragma unroll
  for (int i = 0; i < 16; ++i) acc += z[b * 16 + i] * We[i * 2048 + c];
  seq[gid] = acc;
}

// ---------- decoder init: h fp32 + hb bf16 ----------
__global__ __launch_bounds__(256) void decinit_k(const float* __restrict__ seq, const float* __restrict__ Wc,
    const float* __restrict__ bc, const float* __restrict__ emb, float* __restrict__ h, u16* __restrict__ hb)
{
  size_t gid = (size_t)blockIdx.x * 256 + threadIdx.x;
  int dd = (int)(gid & 511);
  size_t rs = gid >> 9;
  int s = (int)(rs & 1023);
  int b = (int)(rs >> 10);
  float v = seq[b * 2048 + s] * Wc[dd] + seq[b * 2048 + 1024 + s] * Wc[512 + dd]
          + bc[dd] + emb[(size_t)s * 512 + dd];
  h[gid] = v;
  hb[gid] = f2b(v);
}

// ---------- final: out[M,16] = hb[M,512] @ Wseq[512,16] + bs, via MFMA ----------
__global__ __launch_bounds__(256) void finalm_k(const u16* __restrict__ hb, const float* __restrict__ Ws,
    const float* __restrict__ bs, float* __restrict__ out)
{
  __shared__ __align__(16) u16 Wt[16 * 520];
  int t = threadIdx.x;
  for (int e = t; e < 8192; e += 256) {
    int k = e >> 4, n = e & 15;
    Wt[n * 520 + k] = f2b(Ws[e]);
  }
  __syncthreads();
  int lane = t & 63, wave = t >> 6;
  int quad = lane >> 4, l15 = lane & 15;
  int m0 = blockIdx.x * 64 + wave * 16;
  const u16* arow = hb + (size_t)(m0 + l15) * 512 + quad * 8;
  f32x4 acc = (f32x4){0.f, 0.f, 0.f, 0.f};
  #pragma unroll
  for (int ks = 0; ks < 16; ++ks) {
    short8 af = *(const short8*)(arow + ks * 32);
    short8 bf = *(const short8*)&Wt[l15 * 520 + ks * 32 + quad * 8];
    acc = __builtin_amdgcn_mfma_f32_16x16x32_bf16(af, bf, acc, 0, 0, 0);
  }
  #pragma unroll
  for (int r = 0; r < 4; ++r)
    out[(size_t)(m0 + quad * 4 + r) * 16 + l15] = acc[r] + bs[l15];
}

extern "C" void kernel_launch(void* const* d_in, const int* in_sizes, int n_in,
                              void* d_out, int out_size, void* d_ws, size_t ws_size,
                              hipStream_t stream) {
  float* out = (float*)d_out;
  (void)out_size; (void)ws_size;

  static const int EXP_DICT[30] = {
    524288, 512, 524800, 524288, 8192, 512, 7864320, 15360, 2621440, 5120,
    5120, 5120, 10485760, 20480, 10485760, 5120, 5120, 5120, 8192, 16,
    8192, 16, 32768, 2048, 1024, 512, 8192, 16, 387, 384 };
  bool dict_ok = (n_in == 30);
  if (dict_ok) for (int i = 0; i < 30; ++i) if (in_sizes[i] != EXP_DICT[i]) { dict_ok = false; break; }
  if (!dict_ok) { beacon_k<<<1, 64, 0, stream>>>(out); return; }

  const float* x      = (const float*)d_in[0];
  const float* eps    = (const float*)d_in[1];
  const float* emb_in = (const float*)d_in[2];
  const float* emb_out= (const float*)d_in[3];
  const float* W_data = (const float*)d_in[4];
  const float* b_data = (const float*)d_in[5];
  const float* Wqkv   = (const float*)d_in[6];
  const float* bqkv   = (const float*)d_in[7];
  const float* Wo     = (const float*)d_in[8];
  const float* bo     = (const float*)d_in[9];
  const float* ln1g   = (const float*)d_in[10];
  const float* ln1b   = (const float*)d_in[11];
  const float* W1     = (const float*)d_in[12];
  const float* b1     = (const float*)d_in[13];
  const float* W2     = (const float*)d_in[14];
  const float* b2     = (const float*)d_in[15];
  const float* ln2g   = (const float*)d_in[16];
  const float* ln2b   = (const float*)d_in[17];
  const float* Wm     = (const float*)d_in[18];
  const float* bm     = (const float*)d_in[19];
  const float* Wlv    = (const float*)d_in[20];
  const float* blv    = (const float*)d_in[21];
  const float* Wexp   = (const float*)d_in[22];
  const float* bexp   = (const float*)d_in[23];
  const float* Wconv  = (const float*)d_in[24];
  const float* bconv  = (const float*)d_in[25];
  const float* Wseq   = (const float*)d_in[26];
  const float* bseq   = (const float*)d_in[27];
  const int* rand_enc = (const int*)d_in[28];
  const int* rand_dec = (const int*)d_in[29];

  // ---- workspace carve (~194.5 MB; proven-safe envelope 203 MB) ----
  // union region U = [126615552, 194248704):
  //   attn phase: qkvb (50.7 MB) + avb (16.9 MB)
  //   FFN phase:  ffnb = U (16512 x 2048 bf16 = 67,633,152 B exactly)
  char* ws = (char*)d_ws;
  float* h     = (float*)ws;
  u16*   hb    = (u16*)(ws + 67633152);
  u16*   WTqkv = (u16*)(ws + 101449728);
  u16*   WTo   = (u16*)(ws + 117178368);
  u16*   WT1l  = (u16*)(ws + 122421248);
  u16*   WT2l  = (u16*)(ws + 124518400);
  u16*   qkvb  = (u16*)(ws + 126615552);
  u16*   avb   = (u16*)(ws + 126615552 + 50724864);
  u16*   ffnb  = (u16*)(ws + 126615552);             // union reuse
  float* seqb  = (float*)(ws + 194248704);
  float* z     = (float*)(ws + 194510848);

  // ---- persistent weight transpose+convert (qkv, o for all 10 layers) ----
  tr_k<<<dim3(512 / 32, 1536 / 32, 10), 256, 0, stream>>>(Wqkv, WTqkv, 512, 1536);
  tr_k<<<dim3(512 / 32, 512 / 32, 10), 256, 0, stream>>>(Wo, WTo, 512, 512);

  // ===== encoder: M=33024 =====
  {
    const int M = MENC;
    embed_k<<<(M * 512) / 256, 256, 0, stream>>>(x, W_data, b_data, emb_in, h, hb);
    for (int i = 0; i < 5; ++i) {
      // attention path: 2 chunks of 16 batches (Mc=16512)
      for (int bc = 0; bc < 2; ++bc) {
        size_t roff = (size_t)bc * 16 * SPENC * 512;
        const int Mc = 16 * SPENC;  // 16512
        const int ty = 129;         // 16512/128
        mgemm_k<false><<<dim3(6, ty), 512, 0, stream>>>(
            hb + roff, WTqkv + (size_t)i * 512 * 1536, bqkv + (size_t)i * 1536, qkvb, Mc, 1536, 512, 512, 512);
        attnm_k<<<16 * 8 * NBE, 64, 0, stream>>>(qkvb, avb, rand_enc, SENC, SPENC, NBE);
        // fused Wo + residual + LN1
        mgemmln_k<<<ty, 512, 0, stream>>>(
            avb, WTo + (size_t)i * 512 * 512, bo + (size_t)i * 512,
            h + roff, hb + roff, ln1g + (size_t)i * 512, ln1b + (size_t)i * 512, Mc, 512, 512);
      }
      // per-layer FFN weight transposes
      tr_k<<<dim3(512 / 32, 2048 / 32, 1), 256, 0, stream>>>(W1 + (size_t)i * 512 * 2048, WT1l, 512, 2048);
      tr_k<<<dim3(2048 / 32, 512 / 32, 1), 256, 0, stream>>>(W2 + (size_t)i * 2048 * 512, WT2l, 2048, 512);
      // FFN: 2 chunks of 16512 (ffnb = 67.6 MB exactly)
      for (int cc = 0; cc < 2; ++cc) {
        size_t off = (size_t)cc * 16512;
        const int Mc = 16512;
        const int ty = 129;
        mgemm_k<true><<<dim3(8, ty), 512, 0, stream>>>(
            hb + off * 512, WT1l, b1 + (size_t)i * 2048, ffnb, Mc, 2048, 512, 512, 512);
        // fused W2 + residual + LN2
        mgemmln_k<<<ty, 512, 0, stream>>>(
            ffnb, WT2l, b2 + (size_t)i * 512,
            h + off * 512, hb + off * 512, ln2g + (size_t)i * 512, ln2b + (size_t)i * 512, Mc, 2048, 2048);
      }
    }
  }

  // ===== VAE head =====
  head_k<<<1, 512, 0, stream>>>(h, Wm, bm, Wlv, blv, eps, z, out + 524288);
  seq_k<<<256, 256, 0, stream>>>(z, Wexp, bexp, seqb);
  decinit_k<<<(MDEC * 512) / 256, 256, 0, stream>>>(seqb, Wconv, bconv, emb_out, h, hb);

  // ===== decoder: M=32768 =====
  {
    for (int i = 5; i < 10; ++i) {
      for (int bc = 0; bc < 2; ++bc) {
        size_t roff = (size_t)bc * 16 * SDEC * 512;
        const int Mc = 16 * SDEC;  // 16384
        const int ty = 128;
        mgemm_k<false><<<dim3(6, ty), 512, 0, stream>>>(
            hb + roff, WTqkv + (size_t)i * 512 * 1536, bqkv + (size_t)i * 1536, qkvb, Mc, 1536, 512, 512, 512);
        attnm_k<<<16 * 8 * NBD, 64, 0, stream>>>(qkvb, avb, rand_dec, SDEC, SDEC, NBD);
        mgemmln_k<<<ty, 512, 0, stream>>>(
            avb, WTo + (size_t)i * 512 * 512, bo + (size_t)i * 512,
            h + roff, hb + roff, ln1g + (size_t)i * 512, ln1b + (size_t)i * 512, Mc, 512, 512);
      }
      tr_k<<<dim3(512 / 32, 2048 / 32, 1), 256, 0, stream>>>(W1 + (size_t)i * 512 * 2048, WT1l, 512, 2048);
      tr_k<<<dim3(2048 / 32, 512 / 32, 1), 256, 0, stream>>>(W2 + (size_t)i * 2048 * 512, WT2l, 2048, 512);
      for (int cc = 0; cc < 2; ++cc) {
        size_t off = (size_t)cc * 16384;
        const int Mc = 16384;
        const int ty = 128;
        mgemm_k<true><<<dim3(8, ty), 512, 0, stream>>>(
            hb + off * 512, WT1l, b1 + (size_t)i * 2048, ffnb, Mc, 2048, 512, 512, 512);
        mgemmln_k<<<ty, 512, 0, stream>>>(
            ffnb, WT2l, b2 + (size_t)i * 512,
            h + off * 512, hb + off * 512, ln2g + (size_t)i * 512, ln2b + (size_t)i * 512, Mc, 2048, 2048);
      }
    }
  }

  // ===== output =====
  finalm_k<<<MDEC / 64, 256, 0, stream>>>(hb, Wseq, bseq, out);
}